// Round 2
// baseline (4219.013 us; speedup 1.0000x reference)
//
#include <hip/hip_runtime.h>
#include <math.h>

#define ALPHA_ 0.2f

constexpr int B_ = 8, LATENT_ = 256, T_ = 128, N_ = 768, F_ = 4, L_ = 3, E_ = 12288;
constexpr int M_ = B_ * N_;        // 6144 nodes
constexpr int MT_ = B_ * T_;       // 1024 gemm rows
constexpr int EP_ = E_ + M_;       // 18432 edges incl self loops
constexpr size_t SZ_ = (size_t)B_ * T_ * N_ * F_;  // 3145728 == F*M*T == F*MT*N

__device__ __forceinline__ float lrelu(float x) { return x > 0.0f ? x : ALPHA_ * x; }
__device__ __forceinline__ unsigned fenc(float x) {
    unsigned u = __float_as_uint(x);
    return (u & 0x80000000u) ? ~u : (u | 0x80000000u);
}
__device__ __forceinline__ float fdec(unsigned u) {
    return (u & 0x80000000u) ? __uint_as_float(u & 0x7fffffffu) : __uint_as_float(~u);
}

// ---------------- shunt ----------------
__global__ void k_dense(const float* __restrict__ x, const float* __restrict__ w,
                        const float* __restrict__ b, float* __restrict__ y0) {
    int i = blockIdx.x * blockDim.x + threadIdx.x;
    if (i >= B_ * T_) return;
    int bb = i / T_, t = i % T_;
    float acc = b[t];
    for (int l = 0; l < LATENT_; ++l) acc += x[bb * LATENT_ + l] * w[l * T_ + t];
    y0[i] = acc;
}

__global__ void k_conv1(const float* __restrict__ y0, const float* __restrict__ w,
                        const float* __restrict__ b, float* __restrict__ y1) {
    int i = blockIdx.x * blockDim.x + threadIdx.x;
    if (i >= B_ * T_ * N_) return;
    int n = i % N_, t = (i / N_) % T_, bb = i / (N_ * T_);
    float acc = b[n];
    #pragma unroll
    for (int k = 0; k < 3; ++k) {
        int tt = t - 1 + k;
        if (tt >= 0 && tt < T_) acc += y0[bb * T_ + tt] * w[k * N_ + n];
    }
    y1[i] = acc;
}

__global__ void k_conv2(const float* __restrict__ y1, const float* __restrict__ w,
                        const float* __restrict__ b, float* __restrict__ y) {
    int i = blockIdx.x * blockDim.x + threadIdx.x;
    if (i >= B_ * T_ * N_) return;
    int n = i % N_, t = (i / N_) % T_, bb = i / (N_ * T_);
    float acc[F_];
    #pragma unroll
    for (int f = 0; f < F_; ++f) acc[f] = b[f];
    #pragma unroll
    for (int dt = 0; dt < 3; ++dt) {
        int tt = t - 1 + dt;
        if (tt < 0 || tt >= T_) continue;
        #pragma unroll
        for (int dn = 0; dn < 3; ++dn) {
            int nn = n - 1 + dn;
            if (nn < 0 || nn >= N_) continue;
            float v = y1[(bb * T_ + tt) * N_ + nn];
            #pragma unroll
            for (int f = 0; f < F_; ++f) acc[f] += v * w[(dt * 3 + dn) * F_ + f];
        }
    }
    #pragma unroll
    for (int f = 0; f < F_; ++f) y[(size_t)i * F_ + f] = acc[f];
}

// ---------------- layer helpers ----------------
// xT[f][b][t][n] = y[b][t][n][f]
__global__ void k_xT(const float* __restrict__ y, float* __restrict__ xT) {
    size_t i = (size_t)blockIdx.x * blockDim.x + threadIdx.x;
    if (i >= SZ_) return;
    int n = i % N_;
    int t = (i / N_) % T_;
    int bb = (i / ((size_t)N_ * T_)) % B_;
    int f = i / ((size_t)N_ * T_ * B_);
    xT[i] = y[(((size_t)bb * T_ + t) * N_ + n) * F_ + f];
}

// C[f][m][n] = sum_{k,nin} A[f][m-4+k][nin] * W[f][k][nin][n] + bias[f][n]
__global__ __launch_bounds__(256) void k_tcn_gemm(const float* __restrict__ xT,
        const float* __restrict__ wbase, const float* __restrict__ bbase,
        float* __restrict__ out) {
    __shared__ float As[16][65];
    __shared__ float Bs[16][65];
    const int f = blockIdx.z;
    const int n0 = blockIdx.x * 64;
    const int m0 = blockIdx.y * 64;
    const float* xf = xT + (size_t)f * MT_ * N_;
    const float* wf = wbase + (size_t)f * 5 * N_ * N_;
    const int tid = threadIdx.x;
    const int tx = tid & 15, ty = tid >> 4;
    const int lk = tid & 15;    // A tile: k
    const int lm0 = tid >> 4;   // A tile: m base
    const int bk0 = tid >> 6;   // B tile: k base
    const int bn = tid & 63;    // B tile: n
    float c[4][4] = {};
    for (int kk0 = 0; kk0 < 5 * N_; kk0 += 16) {
        const int ks = kk0 / N_;       // conv tap (constant within chunk: 16|768)
        const int nin0 = kk0 % N_;
        #pragma unroll
        for (int p = 0; p < 4; ++p) {
            int lm = lm0 + p * 16;
            int m = m0 + lm;
            int t = m & (T_ - 1);
            int bb = m >> 7;
            int tt = t - 4 + ks;
            As[lk][lm] = (tt >= 0) ? xf[((size_t)bb * T_ + tt) * N_ + nin0 + lk] : 0.0f;
        }
        #pragma unroll
        for (int p = 0; p < 4; ++p) {
            int r = bk0 + p * 4;
            Bs[r][bn] = wf[(size_t)(kk0 + r) * N_ + n0 + bn];
        }
        __syncthreads();
        #pragma unroll
        for (int kk = 0; kk < 16; ++kk) {
            float a[4], bv[4];
            #pragma unroll
            for (int i = 0; i < 4; ++i) a[i] = As[kk][ty * 4 + i];
            #pragma unroll
            for (int j = 0; j < 4; ++j) bv[j] = Bs[kk][tx * 4 + j];
            #pragma unroll
            for (int i = 0; i < 4; ++i)
                #pragma unroll
                for (int j = 0; j < 4; ++j) c[i][j] += a[i] * bv[j];
        }
        __syncthreads();
    }
    const float* bf = bbase + f * N_;
    float* of = out + (size_t)f * MT_ * N_;
    #pragma unroll
    for (int i = 0; i < 4; ++i) {
        int m = m0 + ty * 4 + i;
        #pragma unroll
        for (int j = 0; j < 4; ++j) {
            int n = n0 + tx * 4 + j;
            of[(size_t)m * N_ + n] = c[i][j] + bf[n];
        }
    }
}

__global__ void k_gating(float* __restrict__ a, const float* __restrict__ b) {
    size_t i = (size_t)blockIdx.x * blockDim.x + threadIdx.x;
    if (i >= SZ_) return;
    float av = a[i], bv = b[i];
    float sg = 1.0f / (1.0f + expf(-av));
    a[i] = sg * tanhf(bv);
}

// nodes[f][b*N+n][t] = g[f][b][t][n]
__global__ void k_nodes(const float* __restrict__ g, float* __restrict__ nodes) {
    size_t i = (size_t)blockIdx.x * blockDim.x + threadIdx.x;
    if (i >= SZ_) return;
    int t = i % T_;
    int m = (i / T_) % M_;
    int f = i / ((size_t)T_ * M_);
    int bb = m / N_, n = m % N_;
    nodes[i] = g[(size_t)f * MT_ * N_ + ((size_t)bb * T_ + t) * N_ + n];
}

// C[f][m][n] = epi(nodes[f][m][:] @ W[f][:][n] + bias)
__global__ __launch_bounds__(256) void k_proj(const float* __restrict__ nodes,
        const float* __restrict__ wbase, const float* __restrict__ bbase,
        int do_lrelu, float* __restrict__ out) {
    __shared__ float As[16][65];
    __shared__ float Bs[16][65];
    const int f = blockIdx.z;
    const int n0 = blockIdx.x * 64;
    const int m0 = blockIdx.y * 64;
    const float* af = nodes + (size_t)f * M_ * T_;
    const float* wf = wbase + (size_t)f * T_ * T_;
    const int tid = threadIdx.x;
    const int tx = tid & 15, ty = tid >> 4;
    const int lk = tid & 15;
    const int lm0 = tid >> 4;
    const int bk0 = tid >> 6;
    const int bn = tid & 63;
    float c[4][4] = {};
    for (int kk0 = 0; kk0 < T_; kk0 += 16) {
        #pragma unroll
        for (int p = 0; p < 4; ++p) {
            int lm = lm0 + p * 16;
            As[lk][lm] = af[(size_t)(m0 + lm) * T_ + kk0 + lk];
        }
        #pragma unroll
        for (int p = 0; p < 4; ++p) {
            int r = bk0 + p * 4;
            Bs[r][bn] = wf[(size_t)(kk0 + r) * T_ + n0 + bn];
        }
        __syncthreads();
        #pragma unroll
        for (int kk = 0; kk < 16; ++kk) {
            float a[4], bv[4];
            #pragma unroll
            for (int i = 0; i < 4; ++i) a[i] = As[kk][ty * 4 + i];
            #pragma unroll
            for (int j = 0; j < 4; ++j) bv[j] = Bs[kk][tx * 4 + j];
            #pragma unroll
            for (int i = 0; i < 4; ++i)
                #pragma unroll
                for (int j = 0; j < 4; ++j) c[i][j] += a[i] * bv[j];
        }
        __syncthreads();
    }
    float* of = out + (size_t)f * M_ * T_;
    #pragma unroll
    for (int i = 0; i < 4; ++i) {
        int m = m0 + ty * 4 + i;
        #pragma unroll
        for (int j = 0; j < 4; ++j) {
            int n = n0 + tx * 4 + j;
            float v = c[i][j];
            if (bbase) v += bbase[f * T_ + n];
            if (do_lrelu) v = lrelu(v);
            of[(size_t)m * T_ + n] = v;
        }
    }
}

__device__ __forceinline__ int edge_row(const int* e, int i) { return i < E_ ? e[i] : i - E_; }
__device__ __forceinline__ int edge_col(const int* e, int i) { return i < E_ ? e[E_ + i] : i - E_; }

// one wave per (f, edge): score + atomic segment max
__global__ __launch_bounds__(256) void k_score(const float* __restrict__ Q,
        const float* __restrict__ K, const int* __restrict__ edges,
        float* __restrict__ score, unsigned* __restrict__ smax) {
    int wv = blockIdx.x * 4 + (threadIdx.x >> 6);
    int lane = threadIdx.x & 63;
    if (wv >= F_ * EP_) return;
    int f = wv / EP_, e = wv % EP_;
    int r = edge_row(edges, e), c = edge_col(edges, e);
    const float* Qr = Q + ((size_t)f * M_ + r) * T_;
    const float* Kc = K + ((size_t)f * M_ + c) * T_;
    float s = Qr[lane] * Kc[lane] + Qr[lane + 64] * Kc[lane + 64];
    #pragma unroll
    for (int mk = 32; mk >= 1; mk >>= 1) s += __shfl_xor(s, mk);
    s *= 0.0883883476483184f;   // 1/sqrt(128)
    if (lane == 0) {
        score[(size_t)f * EP_ + e] = s;
        atomicMax(&smax[f * M_ + r], fenc(s));
    }
}

__global__ void k_exden(float* __restrict__ score, const unsigned* __restrict__ smax,
                        float* __restrict__ den, const int* __restrict__ edges) {
    int i = blockIdx.x * blockDim.x + threadIdx.x;
    if (i >= F_ * EP_) return;
    int f = i / EP_, e = i % EP_;
    int r = edge_row(edges, e);
    float ex = expf(score[i] - fdec(smax[f * M_ + r]));
    score[i] = ex;
    atomicAdd(&den[f * M_ + r], ex);
}

// one wave per (f, edge): H[f][r][:] += V[f][c][:] * att
__global__ __launch_bounds__(256) void k_agg(const float* __restrict__ ex,
        const float* __restrict__ den, const float* __restrict__ V,
        const int* __restrict__ edges, float* __restrict__ H) {
    int wv = blockIdx.x * 4 + (threadIdx.x >> 6);
    int lane = threadIdx.x & 63;
    if (wv >= F_ * EP_) return;
    int f = wv / EP_, e = wv % EP_;
    int r = edge_row(edges, e), c = edge_col(edges, e);
    float att = ex[(size_t)f * EP_ + e] / den[f * M_ + r];
    const float* Vc = V + ((size_t)f * M_ + c) * T_;
    float* Hr = H + ((size_t)f * M_ + r) * T_;
    atomicAdd(&Hr[lane], Vc[lane] * att);
    atomicAdd(&Hr[lane + 64], Vc[lane + 64] * att);
}

// y_next[b,t,n,g] = H[g][b*N+n][t] + vb[g][t] + sum_f y[b,t,n,f]*rw[f][g] + rb[g]
// skip[b,t,n] = lrelu(sum_g y_next*skw[layer][g] + skb[layer])
__global__ void k_combine(const float* __restrict__ y, const float* __restrict__ H,
        const float* __restrict__ vb, const float* __restrict__ rw,
        const float* __restrict__ rb, const float* __restrict__ skw,
        const float* __restrict__ skb, int layer,
        float* __restrict__ ynext, float* __restrict__ sbuf) {
    int i = blockIdx.x * blockDim.x + threadIdx.x;
    if (i >= B_ * T_ * N_) return;
    int n = i % N_, t = (i / N_) % T_, bb = i / (N_ * T_);
    int m = bb * N_ + n;
    float yv[F_];
    const float4 y4 = *(const float4*)(y + (size_t)i * F_);
    yv[0] = y4.x; yv[1] = y4.y; yv[2] = y4.z; yv[3] = y4.w;
    float o[F_];
    #pragma unroll
    for (int g = 0; g < F_; ++g) {
        float acc = H[((size_t)g * M_ + m) * T_ + t] + vb[g * T_ + t] + rb[g];
        #pragma unroll
        for (int f2 = 0; f2 < F_; ++f2) acc += yv[f2] * rw[f2 * F_ + g];
        o[g] = acc;
    }
    float4 o4 = {o[0], o[1], o[2], o[3]};
    *(float4*)(ynext + (size_t)i * F_) = o4;
    float sk = skb[layer];
    #pragma unroll
    for (int g = 0; g < F_; ++g) sk += o[g] * skw[layer * F_ + g];   // FIX: per-layer skip weights
    sbuf[(size_t)i * L_ + layer] = lrelu(sk);
}

__global__ void k_final(const float* __restrict__ sbuf, const float* __restrict__ o1w,
        const float* __restrict__ o1b, const float* __restrict__ o2w,
        const float* __restrict__ o2b, float* __restrict__ out) {
    int i = blockIdx.x * blockDim.x + threadIdx.x;
    if (i >= B_ * T_ * N_) return;
    int n = i % N_, t = (i / N_) % T_, bb = i / (N_ * T_);
    float acc = o1b[0];
    #pragma unroll
    for (int dt = 0; dt < 3; ++dt) {
        int tt = t - 1 + dt;
        if (tt < 0 || tt >= T_) continue;
        #pragma unroll
        for (int dn = 0; dn < 3; ++dn) {
            int nn = n - 1 + dn;
            if (nn < 0 || nn >= N_) continue;
            const float* sp = sbuf + ((size_t)(bb * T_ + tt) * N_ + nn) * L_;
            #pragma unroll
            for (int l = 0; l < L_; ++l) acc += sp[l] * o1w[(dt * 3 + dn) * L_ + l];
        }
    }
    float g = lrelu(acc);
    out[i] = g * o2w[0] + o2b[0];
}

extern "C" void kernel_launch(void* const* d_in, const int* in_sizes, int n_in,
                              void* d_out, int out_size, void* d_ws, size_t ws_size,
                              hipStream_t stream) {
    const float* x       = (const float*)d_in[0];
    const int*   edges   = (const int*)d_in[1];
    const float* sd_w    = (const float*)d_in[2];
    const float* sd_b    = (const float*)d_in[3];
    const float* c1w     = (const float*)d_in[4];
    const float* c1b     = (const float*)d_in[5];
    const float* c2w     = (const float*)d_in[6];
    const float* c2b     = (const float*)d_in[7];
    const float* tcn_a_w = (const float*)d_in[8];
    const float* tcn_a_b = (const float*)d_in[9];
    const float* tcn_b_w = (const float*)d_in[10];
    const float* tcn_b_b = (const float*)d_in[11];
    const float* gat_q_w = (const float*)d_in[12];
    const float* gat_q_b = (const float*)d_in[13];
    const float* gat_k_w = (const float*)d_in[14];
    const float* gat_k_b = (const float*)d_in[15];
    const float* gat_v_w = (const float*)d_in[16];
    const float* gat_v_b = (const float*)d_in[17];
    const float* res_w   = (const float*)d_in[18];
    const float* res_b   = (const float*)d_in[19];
    const float* skip_w  = (const float*)d_in[20];
    const float* skip_b  = (const float*)d_in[21];
    const float* out1_w  = (const float*)d_in[22];
    const float* out1_b  = (const float*)d_in[23];
    const float* out2_w  = (const float*)d_in[24];
    const float* out2_b  = (const float*)d_in[25];
    float* out = (float*)d_out;

    float* ws = (float*)d_ws;
    size_t off = 0;
    auto alloc = [&](size_t nf) { float* p = ws + off; off += nf; return p; };
    float* ybuf  = alloc(SZ_);
    float* y2buf = alloc(SZ_);
    float* xT    = alloc(SZ_);            // reused as H
    float* apre  = alloc(SZ_);            // reused as g
    float* bpre  = alloc(SZ_);            // reused as nodes
    float* Q     = alloc(SZ_);
    float* Kb    = alloc(SZ_);
    float* V     = alloc(SZ_);
    float* sbuf  = alloc((size_t)B_ * T_ * N_ * L_);
    float* y0    = alloc(MT_);
    float* y1    = alloc((size_t)B_ * T_ * N_);
    float* score = alloc((size_t)F_ * EP_);
    float* smax  = alloc((size_t)F_ * M_);
    float* den   = alloc((size_t)F_ * M_);
    (void)ws_size; (void)in_sizes; (void)n_in; (void)out_size;

    const int BTN = B_ * T_ * N_;
    // shunt
    k_dense<<<(B_ * T_ + 255) / 256, 256, 0, stream>>>(x, sd_w, sd_b, y0);
    k_conv1<<<(BTN + 255) / 256, 256, 0, stream>>>(y0, c1w, c1b, y1);
    k_conv2<<<(BTN + 255) / 256, 256, 0, stream>>>(y1, c2w, c2b, ybuf);

    float* cur = ybuf;
    float* nxt = y2buf;
    for (int layer = 0; layer < L_; ++layer) {
        const float* wa = tcn_a_w + (size_t)layer * F_ * 5 * N_ * N_;
        const float* ba = tcn_a_b + (size_t)layer * F_ * N_;
        const float* wb = tcn_b_w + (size_t)layer * F_ * 5 * N_ * N_;
        const float* bb = tcn_b_b + (size_t)layer * F_ * N_;
        const float* qw = gat_q_w + (size_t)layer * F_ * T_ * T_;
        const float* qb = gat_q_b + (size_t)layer * F_ * T_;
        const float* kw = gat_k_w + (size_t)layer * F_ * T_ * T_;
        const float* kbias = gat_k_b + (size_t)layer * F_ * T_;
        const float* vw = gat_v_w + (size_t)layer * F_ * T_ * T_;
        const float* vb = gat_v_b + (size_t)layer * F_ * T_;
        const float* rw = res_w + (size_t)layer * F_ * F_;
        const float* rb = res_b + (size_t)layer * F_;

        k_xT<<<(int)((SZ_ + 255) / 256), 256, 0, stream>>>(cur, xT);
        dim3 gt(N_ / 64, MT_ / 64, F_);
        k_tcn_gemm<<<gt, 256, 0, stream>>>(xT, wa, ba, apre);
        k_tcn_gemm<<<gt, 256, 0, stream>>>(xT, wb, bb, bpre);
        k_gating<<<(int)((SZ_ + 255) / 256), 256, 0, stream>>>(apre, bpre);
        k_nodes<<<(int)((SZ_ + 255) / 256), 256, 0, stream>>>(apre, bpre);
        dim3 gp(T_ / 64, M_ / 64, F_);
        k_proj<<<gp, 256, 0, stream>>>(bpre, qw, qb, 1, Q);
        k_proj<<<gp, 256, 0, stream>>>(bpre, kw, kbias, 1, Kb);
        k_proj<<<gp, 256, 0, stream>>>(bpre, vw, nullptr, 0, V);
        hipMemsetAsync(smax, 0, (size_t)F_ * M_ * 4, stream);
        hipMemsetAsync(den, 0, (size_t)F_ * M_ * 4, stream);
        hipMemsetAsync(xT, 0, SZ_ * 4, stream);   // xT now reused as H
        k_score<<<(F_ * EP_) / 4, 256, 0, stream>>>(Q, Kb, edges, score, (unsigned*)smax);
        k_exden<<<(F_ * EP_ + 255) / 256, 256, 0, stream>>>(score, (const unsigned*)smax, den, edges);
        k_agg<<<(F_ * EP_) / 4, 256, 0, stream>>>(score, den, V, edges, xT);
        k_combine<<<(BTN + 255) / 256, 256, 0, stream>>>(cur, xT, vb, rw, rb,
                skip_w, skip_b, layer, nxt, sbuf);
        float* tmp = cur; cur = nxt; nxt = tmp;
    }
    k_final<<<(BTN + 255) / 256, 256, 0, stream>>>(sbuf, out1_w, out1_b, out2_w, out2_b, out);
}

// Round 3
// 1155.313 us; speedup vs baseline: 3.6518x; 3.6518x over previous
//
#include <hip/hip_runtime.h>
#include <math.h>

#define ALPHA_ 0.2f

constexpr int B_ = 8, LATENT_ = 256, T_ = 128, N_ = 768, F_ = 4, L_ = 3, E_ = 12288;
constexpr int M_ = B_ * N_;        // 6144 nodes
constexpr int MT_ = B_ * T_;       // 1024 gemm rows
constexpr int EP_ = E_ + M_;       // 18432 edges incl self loops
constexpr int BTN_ = B_ * T_ * N_; // 786432
constexpr size_t SZ_ = (size_t)BTN_ * F_;  // 3145728
constexpr int KTCN_ = 5 * N_;      // 3840

typedef __bf16 bf16x8 __attribute__((ext_vector_type(8)));
typedef float f32x4 __attribute__((ext_vector_type(4)));

__device__ __forceinline__ float lrelu(float x) { return x > 0.0f ? x : ALPHA_ * x; }
__device__ __forceinline__ unsigned short f2bf(float x) {
    union { __bf16 h; unsigned short u; } c; c.h = (__bf16)x; return c.u;
}
__device__ __forceinline__ unsigned fenc(float x) {
    unsigned u = __float_as_uint(x);
    return (u & 0x80000000u) ? ~u : (u | 0x80000000u);
}
__device__ __forceinline__ float fdec(unsigned u) {
    return (u & 0x80000000u) ? __uint_as_float(u & 0x7fffffffu) : __uint_as_float(~u);
}

// ---------------- shunt ----------------
__global__ void k_dense(const float* __restrict__ x, const float* __restrict__ w,
                        const float* __restrict__ b, float* __restrict__ y0) {
    int i = blockIdx.x * blockDim.x + threadIdx.x;
    if (i >= B_ * T_) return;
    int bb = i / T_, t = i % T_;
    float acc = b[t];
    for (int l = 0; l < LATENT_; ++l) acc += x[bb * LATENT_ + l] * w[l * T_ + t];
    y0[i] = acc;
}

__global__ void k_conv1(const float* __restrict__ y0, const float* __restrict__ w,
                        const float* __restrict__ b, float* __restrict__ y1) {
    int i = blockIdx.x * blockDim.x + threadIdx.x;
    if (i >= BTN_) return;
    int n = i % N_, t = (i / N_) % T_, bb = i / (N_ * T_);
    float acc = b[n];
    #pragma unroll
    for (int k = 0; k < 3; ++k) {
        int tt = t - 1 + k;
        if (tt >= 0 && tt < T_) acc += y0[bb * T_ + tt] * w[k * N_ + n];
    }
    y1[i] = acc;
}

__global__ void k_conv2(const float* __restrict__ y1, const float* __restrict__ w,
                        const float* __restrict__ b, float* __restrict__ y) {
    int i = blockIdx.x * blockDim.x + threadIdx.x;
    if (i >= BTN_) return;
    int n = i % N_, t = (i / N_) % T_, bb = i / (N_ * T_);
    float acc[F_];
    #pragma unroll
    for (int f = 0; f < F_; ++f) acc[f] = b[f];
    #pragma unroll
    for (int dt = 0; dt < 3; ++dt) {
        int tt = t - 1 + dt;
        if (tt < 0 || tt >= T_) continue;
        #pragma unroll
        for (int dn = 0; dn < 3; ++dn) {
            int nn = n - 1 + dn;
            if (nn < 0 || nn >= N_) continue;
            float v = y1[(bb * T_ + tt) * N_ + nn];
            #pragma unroll
            for (int f = 0; f < F_; ++f) acc[f] += v * w[(dt * 3 + dn) * F_ + f];
        }
    }
    #pragma unroll
    for (int f = 0; f < F_; ++f) y[(size_t)i * F_ + f] = acc[f];
}

// ---------------- bf16 plumbing ----------------
// xT[f][b][t][n] = bf16(y[b][t][n][f])
__global__ void k_y2xt(const float* __restrict__ y, unsigned short* __restrict__ xT) {
    int i = blockIdx.x * blockDim.x + threadIdx.x;
    if (i >= BTN_) return;
    const float4 v = *(const float4*)(y + (size_t)i * 4);
    xT[i] = f2bf(v.x);
    xT[(size_t)BTN_ + i] = f2bf(v.y);
    xT[2 * (size_t)BTN_ + i] = f2bf(v.z);
    xT[3 * (size_t)BTN_ + i] = f2bf(v.w);
}

// outT[f][n][k] = bf16(in[f][k][n]); grid (Nd/32, Kd/32, F), 256 threads
__global__ __launch_bounds__(256) void k_convT(const float* __restrict__ in,
        unsigned short* __restrict__ outT, int Kd, int Nd) {
    __shared__ float tl[32][33];
    const int f = blockIdx.z;
    in += (size_t)f * Kd * Nd;
    outT += (size_t)f * Kd * Nd;
    const int x0 = blockIdx.x * 32;   // n
    const int y0 = blockIdx.y * 32;   // k
    const int tx = threadIdx.x & 31, ty = threadIdx.x >> 5;
    #pragma unroll
    for (int r = 0; r < 4; ++r)
        tl[ty + r * 8][tx] = in[(size_t)(y0 + ty + r * 8) * Nd + x0 + tx];
    __syncthreads();
    #pragma unroll
    for (int r = 0; r < 4; ++r)
        outT[(size_t)(x0 + ty + r * 8) * Kd + y0 + tx] = f2bf(tl[tx][ty + r * 8]);
}

// ---------------- TCN GEMM (bf16 MFMA) ----------------
// out[f][b*T+t][n] = sum_{ks,nin} xT[f][b][t-4+ks][nin] * W[f][ks][nin][n] + bias[f][n]
// wt is pre-transposed: wt[f][n][k], k = ks*N+nin
__global__ __launch_bounds__(256) void k_tcn_mfma(
        const unsigned short* __restrict__ xT, const unsigned short* __restrict__ wt,
        const float* __restrict__ bbase, float* __restrict__ out) {
    __shared__ unsigned short As[128][40];
    __shared__ unsigned short Bs[128][40];
    const int f = blockIdx.z;
    const int n0 = blockIdx.x * 128;
    const int bt = blockIdx.y;                       // m-tile == one batch (T_==128)
    const unsigned short* xf = xT + (size_t)(f * B_ + bt) * T_ * N_;
    const unsigned short* wf = wt + (size_t)f * N_ * KTCN_;
    const int tid = threadIdx.x;
    const int srow = tid >> 2;                       // 0..63
    const int col8 = (tid & 3) * 8;                  // 0,8,16,24
    const int lane = tid & 63;
    const int w = tid >> 6;
    const int wm = (w >> 1) * 64, wn = (w & 1) * 64;
    const int r16 = lane & 15, kb = lane >> 4;
    f32x4 acc[4][4] = {};
    for (int kk0 = 0; kk0 < KTCN_; kk0 += 32) {
        const int ks = kk0 / N_;                     // 32 | 768 -> constant per chunk
        const int nin0 = kk0 % N_;
        #pragma unroll
        for (int h = 0; h < 2; ++h) {
            const int lm = srow + h * 64;
            const int tt = lm - 4 + ks;
            uint4 va = make_uint4(0u, 0u, 0u, 0u);
            if (tt >= 0) va = *(const uint4*)(xf + (size_t)tt * N_ + nin0 + col8);
            *(uint4*)&As[lm][col8] = va;
            const uint4 vb = *(const uint4*)(wf + (size_t)(n0 + lm) * KTCN_ + kk0 + col8);
            *(uint4*)&Bs[lm][col8] = vb;
        }
        __syncthreads();
        bf16x8 av[4], bv[4];
        #pragma unroll
        for (int i = 0; i < 4; ++i) av[i] = *(const bf16x8*)&As[wm + i * 16 + r16][kb * 8];
        #pragma unroll
        for (int j = 0; j < 4; ++j) bv[j] = *(const bf16x8*)&Bs[wn + j * 16 + r16][kb * 8];
        #pragma unroll
        for (int i = 0; i < 4; ++i)
            #pragma unroll
            for (int j = 0; j < 4; ++j)
                acc[i][j] = __builtin_amdgcn_mfma_f32_16x16x32_bf16(av[i], bv[j], acc[i][j], 0, 0, 0);
        __syncthreads();
    }
    const float* bf = bbase + f * N_;
    float* of = out + (size_t)(f * B_ + bt) * T_ * N_;
    #pragma unroll
    for (int i = 0; i < 4; ++i) {
        #pragma unroll
        for (int j = 0; j < 4; ++j) {
            const int n = n0 + wn + j * 16 + r16;
            #pragma unroll
            for (int r = 0; r < 4; ++r) {
                const int m = wm + i * 16 + kb * 4 + r;
                of[(size_t)m * N_ + n] = acc[i][j][r] + bf[n];
            }
        }
    }
}

// ---------------- gating + transpose to node layout ----------------
// nodes[f][b][n][t] = bf16(sigmoid(a[f][b][t][n]) * tanh(b[f][b][t][n]))
__global__ __launch_bounds__(256) void k_gate_nodes(const float* __restrict__ a,
        const float* __restrict__ b, unsigned short* __restrict__ nodes) {
    __shared__ float tl[32][33];
    const int bz = blockIdx.z;                       // f*B + b
    const int t0 = blockIdx.x * 32, n0 = blockIdx.y * 32;
    const int tx = threadIdx.x & 31, ty = threadIdx.x >> 5;
    const size_t base = (size_t)bz * T_ * N_;
    #pragma unroll
    for (int r = 0; r < 4; ++r) {
        const size_t idx = base + (size_t)(t0 + ty + r * 8) * N_ + n0 + tx;
        const float av = a[idx], bvv = b[idx];
        tl[ty + r * 8][tx] = (1.0f / (1.0f + __expf(-av))) * tanhf(bvv);
    }
    __syncthreads();
    #pragma unroll
    for (int r = 0; r < 4; ++r)
        nodes[base + (size_t)(n0 + ty + r * 8) * T_ + t0 + tx] = f2bf(tl[tx][ty + r * 8]);
}

// ---------------- GAT projection GEMM (bf16 MFMA, K=128) ----------------
// out[f][m][n] = epi(nodes[f][m][:] @ W[f][:][n] + bias);  wt[f][n][k] transposed
__global__ __launch_bounds__(256) void k_proj_mfma(
        const unsigned short* __restrict__ nodes, const unsigned short* __restrict__ wt,
        const float* __restrict__ bbase, int do_lrelu, float* __restrict__ out) {
    __shared__ unsigned short As[128][40];
    __shared__ unsigned short Bs[128][40];
    const int f = blockIdx.z;
    const int m0 = blockIdx.y * 128;
    const unsigned short* af = nodes + (size_t)f * M_ * T_;
    const unsigned short* wf = wt + (size_t)f * T_ * T_;
    const int tid = threadIdx.x;
    const int srow = tid >> 2;
    const int col8 = (tid & 3) * 8;
    const int lane = tid & 63;
    const int w = tid >> 6;
    const int wm = (w >> 1) * 64, wn = (w & 1) * 64;
    const int r16 = lane & 15, kb = lane >> 4;
    f32x4 acc[4][4] = {};
    for (int kk0 = 0; kk0 < T_; kk0 += 32) {
        #pragma unroll
        for (int h = 0; h < 2; ++h) {
            const int lm = srow + h * 64;
            *(uint4*)&As[lm][col8] = *(const uint4*)(af + (size_t)(m0 + lm) * T_ + kk0 + col8);
            *(uint4*)&Bs[lm][col8] = *(const uint4*)(wf + (size_t)lm * T_ + kk0 + col8);
        }
        __syncthreads();
        bf16x8 av[4], bv[4];
        #pragma unroll
        for (int i = 0; i < 4; ++i) av[i] = *(const bf16x8*)&As[wm + i * 16 + r16][kb * 8];
        #pragma unroll
        for (int j = 0; j < 4; ++j) bv[j] = *(const bf16x8*)&Bs[wn + j * 16 + r16][kb * 8];
        #pragma unroll
        for (int i = 0; i < 4; ++i)
            #pragma unroll
            for (int j = 0; j < 4; ++j)
                acc[i][j] = __builtin_amdgcn_mfma_f32_16x16x32_bf16(av[i], bv[j], acc[i][j], 0, 0, 0);
        __syncthreads();
    }
    float* of = out + (size_t)f * M_ * T_;
    #pragma unroll
    for (int i = 0; i < 4; ++i) {
        #pragma unroll
        for (int j = 0; j < 4; ++j) {
            const int n = wn + j * 16 + r16;
            #pragma unroll
            for (int r = 0; r < 4; ++r) {
                const int m = m0 + wm + i * 16 + kb * 4 + r;
                float v = acc[i][j][r];
                if (bbase) v += bbase[f * T_ + n];
                if (do_lrelu) v = lrelu(v);
                of[(size_t)m * T_ + n] = v;
            }
        }
    }
}

__device__ __forceinline__ int edge_row(const int* e, int i) { return i < E_ ? e[i] : i - E_; }
__device__ __forceinline__ int edge_col(const int* e, int i) { return i < E_ ? e[E_ + i] : i - E_; }

// one wave per (f, edge): score + atomic segment max
__global__ __launch_bounds__(256) void k_score(const float* __restrict__ Q,
        const float* __restrict__ K, const int* __restrict__ edges,
        float* __restrict__ score, unsigned* __restrict__ smax) {
    int wv = blockIdx.x * 4 + (threadIdx.x >> 6);
    int lane = threadIdx.x & 63;
    if (wv >= F_ * EP_) return;
    int f = wv / EP_, e = wv % EP_;
    int r = edge_row(edges, e), c = edge_col(edges, e);
    const float* Qr = Q + ((size_t)f * M_ + r) * T_;
    const float* Kc = K + ((size_t)f * M_ + c) * T_;
    float s = Qr[lane] * Kc[lane] + Qr[lane + 64] * Kc[lane + 64];
    #pragma unroll
    for (int mk = 32; mk >= 1; mk >>= 1) s += __shfl_xor(s, mk);
    s *= 0.0883883476483184f;   // 1/sqrt(128)
    if (lane == 0) {
        score[(size_t)f * EP_ + e] = s;
        atomicMax(&smax[f * M_ + r], fenc(s));
    }
}

__global__ void k_exden(float* __restrict__ score, const unsigned* __restrict__ smax,
                        float* __restrict__ den, const int* __restrict__ edges) {
    int i = blockIdx.x * blockDim.x + threadIdx.x;
    if (i >= F_ * EP_) return;
    int f = i / EP_, e = i % EP_;
    int r = edge_row(edges, e);
    float ex = expf(score[i] - fdec(smax[f * M_ + r]));
    score[i] = ex;
    atomicAdd(&den[f * M_ + r], ex);
}

// one wave per (f, edge): H[f][r][:] += V[f][c][:] * att
__global__ __launch_bounds__(256) void k_agg(const float* __restrict__ ex,
        const float* __restrict__ den, const float* __restrict__ V,
        const int* __restrict__ edges, float* __restrict__ H) {
    int wv = blockIdx.x * 4 + (threadIdx.x >> 6);
    int lane = threadIdx.x & 63;
    if (wv >= F_ * EP_) return;
    int f = wv / EP_, e = wv % EP_;
    int r = edge_row(edges, e), c = edge_col(edges, e);
    float att = ex[(size_t)f * EP_ + e] / den[f * M_ + r];
    const float* Vc = V + ((size_t)f * M_ + c) * T_;
    float* Hr = H + ((size_t)f * M_ + r) * T_;
    atomicAdd(&Hr[lane], Vc[lane] * att);
    atomicAdd(&Hr[lane + 64], Vc[lane + 64] * att);
}

// y_next[b,t,n,g] = H[g][b*N+n][t] + vb[g][t] + sum_f y[b,t,n,f]*rw[f][g] + rb[g]
__global__ void k_combine(const float* __restrict__ y, const float* __restrict__ H,
        const float* __restrict__ vb, const float* __restrict__ rw,
        const float* __restrict__ rb, const float* __restrict__ skw,
        const float* __restrict__ skb, int layer,
        float* __restrict__ ynext, float* __restrict__ sbuf) {
    int i = blockIdx.x * blockDim.x + threadIdx.x;
    if (i >= BTN_) return;
    int n = i % N_, t = (i / N_) % T_, bb = i / (N_ * T_);
    int m = bb * N_ + n;
    float yv[F_];
    const float4 y4 = *(const float4*)(y + (size_t)i * F_);
    yv[0] = y4.x; yv[1] = y4.y; yv[2] = y4.z; yv[3] = y4.w;
    float o[F_];
    #pragma unroll
    for (int g = 0; g < F_; ++g) {
        float acc = H[((size_t)g * M_ + m) * T_ + t] + vb[g * T_ + t] + rb[g];
        #pragma unroll
        for (int f2 = 0; f2 < F_; ++f2) acc += yv[f2] * rw[f2 * F_ + g];
        o[g] = acc;
    }
    float4 o4 = {o[0], o[1], o[2], o[3]};
    *(float4*)(ynext + (size_t)i * F_) = o4;
    float sk = skb[layer];
    #pragma unroll
    for (int g = 0; g < F_; ++g) sk += o[g] * skw[layer * F_ + g];
    sbuf[(size_t)i * L_ + layer] = lrelu(sk);
}

__global__ void k_final(const float* __restrict__ sbuf, const float* __restrict__ o1w,
        const float* __restrict__ o1b, const float* __restrict__ o2w,
        const float* __restrict__ o2b, float* __restrict__ out) {
    int i = blockIdx.x * blockDim.x + threadIdx.x;
    if (i >= BTN_) return;
    int n = i % N_, t = (i / N_) % T_, bb = i / (N_ * T_);
    float acc = o1b[0];
    #pragma unroll
    for (int dt = 0; dt < 3; ++dt) {
        int tt = t - 1 + dt;
        if (tt < 0 || tt >= T_) continue;
        #pragma unroll
        for (int dn = 0; dn < 3; ++dn) {
            int nn = n - 1 + dn;
            if (nn < 0 || nn >= N_) continue;
            const float* sp = sbuf + ((size_t)(bb * T_ + tt) * N_ + nn) * L_;
            #pragma unroll
            for (int l = 0; l < L_; ++l) acc += sp[l] * o1w[(dt * 3 + dn) * L_ + l];
        }
    }
    float g = lrelu(acc);
    out[i] = g * o2w[0] + o2b[0];
}

extern "C" void kernel_launch(void* const* d_in, const int* in_sizes, int n_in,
                              void* d_out, int out_size, void* d_ws, size_t ws_size,
                              hipStream_t stream) {
    const float* x       = (const float*)d_in[0];
    const int*   edges   = (const int*)d_in[1];
    const float* sd_w    = (const float*)d_in[2];
    const float* sd_b    = (const float*)d_in[3];
    const float* c1w     = (const float*)d_in[4];
    const float* c1b     = (const float*)d_in[5];
    const float* c2w     = (const float*)d_in[6];
    const float* c2b     = (const float*)d_in[7];
    const float* tcn_a_w = (const float*)d_in[8];
    const float* tcn_a_b = (const float*)d_in[9];
    const float* tcn_b_w = (const float*)d_in[10];
    const float* tcn_b_b = (const float*)d_in[11];
    const float* gat_q_w = (const float*)d_in[12];
    const float* gat_q_b = (const float*)d_in[13];
    const float* gat_k_w = (const float*)d_in[14];
    const float* gat_k_b = (const float*)d_in[15];
    const float* gat_v_w = (const float*)d_in[16];
    const float* gat_v_b = (const float*)d_in[17];
    const float* res_w   = (const float*)d_in[18];
    const float* res_b   = (const float*)d_in[19];
    const float* skip_w  = (const float*)d_in[20];
    const float* skip_b  = (const float*)d_in[21];
    const float* out1_w  = (const float*)d_in[22];
    const float* out1_b  = (const float*)d_in[23];
    const float* out2_w  = (const float*)d_in[24];
    const float* out2_b  = (const float*)d_in[25];
    float* out = (float*)d_out;

    float* ws = (float*)d_ws;
    size_t off = 0;
    auto alloc = [&](size_t nf) { float* p = ws + off; off += nf; return p; };
    float* ybuf  = alloc(SZ_);
    float* y2buf = alloc(SZ_);
    float* H     = alloc(SZ_);
    float* apre  = alloc(SZ_);            // reused as Q
    float* bpre  = alloc(SZ_);            // reused as K
    float* V     = alloc(SZ_);
    float* sbuf  = alloc((size_t)BTN_ * L_);
    float* y0    = alloc(MT_);
    float* y1    = alloc(BTN_);
    float* score = alloc((size_t)F_ * EP_);
    float* smax  = alloc((size_t)F_ * M_);
    float* den   = alloc((size_t)F_ * M_);
    unsigned short* xTn = (unsigned short*)alloc(SZ_ / 2);            // xT_bf / nodes_bf union
    unsigned short* wat = (unsigned short*)alloc((size_t)F_ * KTCN_ * N_ / 2);
    unsigned short* wbt = (unsigned short*)alloc((size_t)F_ * KTCN_ * N_ / 2);
    unsigned short* pwt = (unsigned short*)alloc((size_t)3 * F_ * T_ * T_ / 2);
    (void)ws_size; (void)in_sizes; (void)n_in; (void)out_size;

    // shunt
    k_dense<<<(B_ * T_ + 255) / 256, 256, 0, stream>>>(x, sd_w, sd_b, y0);
    k_conv1<<<(BTN_ + 255) / 256, 256, 0, stream>>>(y0, c1w, c1b, y1);
    k_conv2<<<(BTN_ + 255) / 256, 256, 0, stream>>>(y1, c2w, c2b, ybuf);

    float* cur = ybuf;
    float* nxt = y2buf;
    const int PWOFF = F_ * T_ * T_;   // bf16 elems per proj-weight tensor
    for (int layer = 0; layer < L_; ++layer) {
        const float* wa = tcn_a_w + (size_t)layer * F_ * KTCN_ * N_;
        const float* ba = tcn_a_b + (size_t)layer * F_ * N_;
        const float* wb = tcn_b_w + (size_t)layer * F_ * KTCN_ * N_;
        const float* bb = tcn_b_b + (size_t)layer * F_ * N_;
        const float* qw = gat_q_w + (size_t)layer * F_ * T_ * T_;
        const float* qb = gat_q_b + (size_t)layer * F_ * T_;
        const float* kw = gat_k_w + (size_t)layer * F_ * T_ * T_;
        const float* kbias = gat_k_b + (size_t)layer * F_ * T_;
        const float* vw = gat_v_w + (size_t)layer * F_ * T_ * T_;
        const float* vb = gat_v_b + (size_t)layer * F_ * T_;
        const float* rw = res_w + (size_t)layer * F_ * F_;
        const float* rb = res_b + (size_t)layer * F_;

        // input -> bf16 planes
        k_y2xt<<<(BTN_ + 255) / 256, 256, 0, stream>>>(cur, xTn);
        // weights -> bf16 transposed
        dim3 gw(N_ / 32, KTCN_ / 32, F_);
        k_convT<<<gw, 256, 0, stream>>>(wa, wat, KTCN_, N_);
        k_convT<<<gw, 256, 0, stream>>>(wb, wbt, KTCN_, N_);
        // TCN GEMMs
        dim3 gt(N_ / 128, B_, F_);
        k_tcn_mfma<<<gt, 256, 0, stream>>>(xTn, wat, ba, apre);
        k_tcn_mfma<<<gt, 256, 0, stream>>>(xTn, wbt, bb, bpre);
        // gating + transpose to nodes (overwrites xTn union)
        dim3 gg(T_ / 32, N_ / 32, F_ * B_);
        k_gate_nodes<<<gg, 256, 0, stream>>>(apre, bpre, xTn);
        // proj weights
        dim3 gpw(T_ / 32, T_ / 32, F_);
        k_convT<<<gpw, 256, 0, stream>>>(qw, pwt, T_, T_);
        k_convT<<<gpw, 256, 0, stream>>>(kw, pwt + PWOFF, T_, T_);
        k_convT<<<gpw, 256, 0, stream>>>(vw, pwt + 2 * PWOFF, T_, T_);
        // projections (Q overlays apre, K overlays bpre)
        dim3 gp(1, M_ / 128, F_);
        k_proj_mfma<<<gp, 256, 0, stream>>>(xTn, pwt, qb, 1, apre);
        k_proj_mfma<<<gp, 256, 0, stream>>>(xTn, pwt + PWOFF, kbias, 1, bpre);
        k_proj_mfma<<<gp, 256, 0, stream>>>(xTn, pwt + 2 * PWOFF, nullptr, 0, V);
        // GAT edge phase
        hipMemsetAsync(smax, 0, (size_t)F_ * M_ * 4, stream);
        hipMemsetAsync(den, 0, (size_t)F_ * M_ * 4, stream);
        hipMemsetAsync(H, 0, SZ_ * 4, stream);
        k_score<<<(F_ * EP_) / 4, 256, 0, stream>>>(apre, bpre, edges, score, (unsigned*)smax);
        k_exden<<<(F_ * EP_ + 255) / 256, 256, 0, stream>>>(score, (const unsigned*)smax, den, edges);
        k_agg<<<(F_ * EP_) / 4, 256, 0, stream>>>(score, den, V, edges, H);
        k_combine<<<(BTN_ + 255) / 256, 256, 0, stream>>>(cur, H, vb, rw, rb,
                skip_w, skip_b, layer, nxt, sbuf);
        float* tmp = cur; cur = nxt; nxt = tmp;
    }
    k_final<<<(BTN_ + 255) / 256, 256, 0, stream>>>(sbuf, out1_w, out1_b, out2_w, out2_b, out);
}

// Round 4
// 777.321 us; speedup vs baseline: 5.4276x; 1.4863x over previous
//
#include <hip/hip_runtime.h>
#include <math.h>

#define ALPHA_ 0.2f

constexpr int B_ = 8, LATENT_ = 256, T_ = 128, N_ = 768, F_ = 4, L_ = 3, E_ = 12288;
constexpr int M_ = B_ * N_;        // 6144 nodes
constexpr int MT_ = B_ * T_;       // 1024 gemm rows
constexpr int EP_ = E_ + M_;       // 18432 edges incl self loops
constexpr int BTN_ = B_ * T_ * N_; // 786432
constexpr size_t SZ_ = (size_t)BTN_ * F_;  // 3145728
constexpr int KTCN_ = 5 * N_;      // 3840
constexpr int KSPLIT_ = KTCN_ / 2; // 1920

typedef __bf16 bf16x8 __attribute__((ext_vector_type(8)));
typedef float f32x4 __attribute__((ext_vector_type(4)));

__device__ __forceinline__ float lrelu(float x) { return x > 0.0f ? x : ALPHA_ * x; }
__device__ __forceinline__ unsigned short f2bf(float x) {
    union { __bf16 h; unsigned short u; } c; c.h = (__bf16)x; return c.u;
}
__device__ __forceinline__ unsigned fenc(float x) {
    unsigned u = __float_as_uint(x);
    return (u & 0x80000000u) ? ~u : (u | 0x80000000u);
}
__device__ __forceinline__ float fdec(unsigned u) {
    return (u & 0x80000000u) ? __uint_as_float(u & 0x7fffffffu) : __uint_as_float(~u);
}

// ---------------- shunt ----------------
__global__ void k_dense(const float* __restrict__ x, const float* __restrict__ w,
                        const float* __restrict__ b, float* __restrict__ y0) {
    int i = blockIdx.x * blockDim.x + threadIdx.x;
    if (i >= B_ * T_) return;
    int bb = i / T_, t = i % T_;
    float acc = b[t];
    for (int l = 0; l < LATENT_; ++l) acc += x[bb * LATENT_ + l] * w[l * T_ + t];
    y0[i] = acc;
}

__global__ void k_conv1(const float* __restrict__ y0, const float* __restrict__ w,
                        const float* __restrict__ b, float* __restrict__ y1) {
    int i = blockIdx.x * blockDim.x + threadIdx.x;
    if (i >= BTN_) return;
    int n = i % N_, t = (i / N_) % T_, bb = i / (N_ * T_);
    float acc = b[n];
    #pragma unroll
    for (int k = 0; k < 3; ++k) {
        int tt = t - 1 + k;
        if (tt >= 0 && tt < T_) acc += y0[bb * T_ + tt] * w[k * N_ + n];
    }
    y1[i] = acc;
}

__global__ void k_conv2(const float* __restrict__ y1, const float* __restrict__ w,
                        const float* __restrict__ b, float* __restrict__ y) {
    int i = blockIdx.x * blockDim.x + threadIdx.x;
    if (i >= BTN_) return;
    int n = i % N_, t = (i / N_) % T_, bb = i / (N_ * T_);
    float acc[F_];
    #pragma unroll
    for (int f = 0; f < F_; ++f) acc[f] = b[f];
    #pragma unroll
    for (int dt = 0; dt < 3; ++dt) {
        int tt = t - 1 + dt;
        if (tt < 0 || tt >= T_) continue;
        #pragma unroll
        for (int dn = 0; dn < 3; ++dn) {
            int nn = n - 1 + dn;
            if (nn < 0 || nn >= N_) continue;
            float v = y1[(bb * T_ + tt) * N_ + nn];
            #pragma unroll
            for (int f = 0; f < F_; ++f) acc[f] += v * w[(dt * 3 + dn) * F_ + f];
        }
    }
    #pragma unroll
    for (int f = 0; f < F_; ++f) y[(size_t)i * F_ + f] = acc[f];
}

// ---------------- bf16 plumbing ----------------
// xT[f][b][t][n] = bf16(y[b][t][n][f])
__global__ void k_y2xt(const float* __restrict__ y, unsigned short* __restrict__ xT) {
    int i = blockIdx.x * blockDim.x + threadIdx.x;
    if (i >= BTN_) return;
    const float4 v = *(const float4*)(y + (size_t)i * 4);
    xT[i] = f2bf(v.x);
    xT[(size_t)BTN_ + i] = f2bf(v.y);
    xT[2 * (size_t)BTN_ + i] = f2bf(v.z);
    xT[3 * (size_t)BTN_ + i] = f2bf(v.w);
}

// outT[f][n][k] = bf16(in[f][k][n]); grid (Nd/32, Kd/32, F), 256 threads
__global__ __launch_bounds__(256) void k_convT(const float* __restrict__ in,
        unsigned short* __restrict__ outT, int Kd, int Nd) {
    __shared__ float tl[32][33];
    const int f = blockIdx.z;
    in += (size_t)f * Kd * Nd;
    outT += (size_t)f * Kd * Nd;
    const int x0 = blockIdx.x * 32;   // n
    const int y0 = blockIdx.y * 32;   // k
    const int tx = threadIdx.x & 31, ty = threadIdx.x >> 5;
    #pragma unroll
    for (int r = 0; r < 4; ++r)
        tl[ty + r * 8][tx] = in[(size_t)(y0 + ty + r * 8) * Nd + x0 + tx];
    __syncthreads();
    #pragma unroll
    for (int r = 0; r < 4; ++r)
        outT[(size_t)(x0 + ty + r * 8) * Kd + y0 + tx] = f2bf(tl[tx][ty + r * 8]);
}

// ---------------- TCN GEMM (bf16 MFMA, a/b fused, split-K=2) ----------------
// z = (s*2 + wsel)*F + f;  out[wsel][s][f][b*T+t][n] partial sums
__global__ __launch_bounds__(256) void k_tcn_mfma(
        const unsigned short* __restrict__ xT,
        const unsigned short* __restrict__ wat, const unsigned short* __restrict__ wbt,
        const float* __restrict__ ba, const float* __restrict__ bbias,
        float* __restrict__ oa0, float* __restrict__ oa1,
        float* __restrict__ ob0, float* __restrict__ ob1) {
    __shared__ unsigned short As[128][40];
    __shared__ unsigned short Bs[128][40];
    const int zz = blockIdx.z;
    const int f = zz & 3;
    const int wsel = (zz >> 2) & 1;
    const int s = zz >> 3;
    const int n0 = blockIdx.x * 128;
    const int bt = blockIdx.y;                       // m-tile == one batch (T_==128)
    const unsigned short* xf = xT + (size_t)(f * B_ + bt) * T_ * N_;
    const unsigned short* wf = (wsel ? wbt : wat) + (size_t)f * N_ * KTCN_;
    const float* bias = (wsel ? bbias : ba) + f * N_;
    float* out = (wsel ? (s ? ob1 : ob0) : (s ? oa1 : oa0));
    const int tid = threadIdx.x;
    const int srow = tid >> 2;                       // 0..63
    const int col8 = (tid & 3) * 8;                  // 0,8,16,24
    const int lane = tid & 63;
    const int w = tid >> 6;
    const int wm = (w >> 1) * 64, wn = (w & 1) * 64;
    const int r16 = lane & 15, kb = lane >> 4;
    f32x4 acc[4][4] = {};
    const int k_lo = s * KSPLIT_, k_hi = k_lo + KSPLIT_;
    for (int kk0 = k_lo; kk0 < k_hi; kk0 += 32) {
        const int ks = kk0 / N_;                     // 32 | 768 -> constant per chunk
        const int nin0 = kk0 % N_;
        #pragma unroll
        for (int h = 0; h < 2; ++h) {
            const int lm = srow + h * 64;
            const int tt = lm - 4 + ks;
            uint4 va = make_uint4(0u, 0u, 0u, 0u);
            if (tt >= 0) va = *(const uint4*)(xf + (size_t)tt * N_ + nin0 + col8);
            *(uint4*)&As[lm][col8] = va;
            const uint4 vb = *(const uint4*)(wf + (size_t)(n0 + lm) * KTCN_ + kk0 + col8);
            *(uint4*)&Bs[lm][col8] = vb;
        }
        __syncthreads();
        bf16x8 av[4], bv[4];
        #pragma unroll
        for (int i = 0; i < 4; ++i) av[i] = *(const bf16x8*)&As[wm + i * 16 + r16][kb * 8];
        #pragma unroll
        for (int j = 0; j < 4; ++j) bv[j] = *(const bf16x8*)&Bs[wn + j * 16 + r16][kb * 8];
        #pragma unroll
        for (int i = 0; i < 4; ++i)
            #pragma unroll
            for (int j = 0; j < 4; ++j)
                acc[i][j] = __builtin_amdgcn_mfma_f32_16x16x32_bf16(av[i], bv[j], acc[i][j], 0, 0, 0);
        __syncthreads();
    }
    float* of = out + (size_t)(f * B_ + bt) * T_ * N_;
    #pragma unroll
    for (int i = 0; i < 4; ++i) {
        #pragma unroll
        for (int j = 0; j < 4; ++j) {
            const int n = n0 + wn + j * 16 + r16;
            const float bv2 = (s == 0) ? bias[n] : 0.0f;
            #pragma unroll
            for (int r = 0; r < 4; ++r) {
                const int m = wm + i * 16 + kb * 4 + r;
                of[(size_t)m * N_ + n] = acc[i][j][r] + bv2;
            }
        }
    }
}

// ---------------- gating (sum split-K partials) + transpose to node layout --------
// nodes[f][b][n][t] = bf16(sigmoid(a0+a1) * tanh(b0+b1))
__global__ __launch_bounds__(256) void k_gate_nodes(const float* __restrict__ a0,
        const float* __restrict__ a1, const float* __restrict__ b0,
        const float* __restrict__ b1, unsigned short* __restrict__ nodes) {
    __shared__ float tl[32][33];
    const int bz = blockIdx.z;                       // f*B + b
    const int t0 = blockIdx.x * 32, n0 = blockIdx.y * 32;
    const int tx = threadIdx.x & 31, ty = threadIdx.x >> 5;
    const size_t base = (size_t)bz * T_ * N_;
    #pragma unroll
    for (int r = 0; r < 4; ++r) {
        const size_t idx = base + (size_t)(t0 + ty + r * 8) * N_ + n0 + tx;
        const float av = a0[idx] + a1[idx], bvv = b0[idx] + b1[idx];
        tl[ty + r * 8][tx] = (1.0f / (1.0f + __expf(-av))) * tanhf(bvv);
    }
    __syncthreads();
    #pragma unroll
    for (int r = 0; r < 4; ++r)
        nodes[base + (size_t)(n0 + ty + r * 8) * T_ + t0 + tx] = f2bf(tl[tx][ty + r * 8]);
}

// ---------------- GAT projection GEMM (bf16 MFMA, K=128, Q/K/V fused) -------------
// z = sel*F + f; sel: 0=Q(lrelu,qb) 1=K(lrelu,kb) 2=V(no epi, no bias)
__global__ __launch_bounds__(256) void k_proj_mfma(
        const unsigned short* __restrict__ nodes, const unsigned short* __restrict__ pwt,
        const float* __restrict__ qb, const float* __restrict__ kbias,
        float* __restrict__ Q, float* __restrict__ K, float* __restrict__ V) {
    __shared__ unsigned short As[128][40];
    __shared__ unsigned short Bs[128][40];
    const int zz = blockIdx.z;
    const int f = zz & 3;
    const int sel = zz >> 2;
    const int m0 = blockIdx.y * 128;
    const unsigned short* af = nodes + (size_t)f * M_ * T_;
    const unsigned short* wf = pwt + (size_t)sel * F_ * T_ * T_ + (size_t)f * T_ * T_;
    const float* bias = (sel == 0) ? qb : (sel == 1 ? kbias : nullptr);
    float* out = (sel == 0) ? Q : (sel == 1 ? K : V);
    const int tid = threadIdx.x;
    const int srow = tid >> 2;
    const int col8 = (tid & 3) * 8;
    const int lane = tid & 63;
    const int w = tid >> 6;
    const int wm = (w >> 1) * 64, wn = (w & 1) * 64;
    const int r16 = lane & 15, kb = lane >> 4;
    f32x4 acc[4][4] = {};
    for (int kk0 = 0; kk0 < T_; kk0 += 32) {
        #pragma unroll
        for (int h = 0; h < 2; ++h) {
            const int lm = srow + h * 64;
            *(uint4*)&As[lm][col8] = *(const uint4*)(af + (size_t)(m0 + lm) * T_ + kk0 + col8);
            *(uint4*)&Bs[lm][col8] = *(const uint4*)(wf + (size_t)lm * T_ + kk0 + col8);
        }
        __syncthreads();
        bf16x8 av[4], bv[4];
        #pragma unroll
        for (int i = 0; i < 4; ++i) av[i] = *(const bf16x8*)&As[wm + i * 16 + r16][kb * 8];
        #pragma unroll
        for (int j = 0; j < 4; ++j) bv[j] = *(const bf16x8*)&Bs[wn + j * 16 + r16][kb * 8];
        #pragma unroll
        for (int i = 0; i < 4; ++i)
            #pragma unroll
            for (int j = 0; j < 4; ++j)
                acc[i][j] = __builtin_amdgcn_mfma_f32_16x16x32_bf16(av[i], bv[j], acc[i][j], 0, 0, 0);
        __syncthreads();
    }
    const int do_l = (sel < 2);
    float* of = out + (size_t)f * M_ * T_;
    #pragma unroll
    for (int i = 0; i < 4; ++i) {
        #pragma unroll
        for (int j = 0; j < 4; ++j) {
            const int n = wn + j * 16 + r16;
            #pragma unroll
            for (int r = 0; r < 4; ++r) {
                const int m = m0 + wm + i * 16 + kb * 4 + r;
                float v = acc[i][j][r];
                if (bias) v += bias[f * T_ + n];
                if (do_l) v = lrelu(v);
                of[(size_t)m * T_ + n] = v;
            }
        }
    }
}

__device__ __forceinline__ int edge_row(const int* e, int i) { return i < E_ ? e[i] : i - E_; }
__device__ __forceinline__ int edge_col(const int* e, int i) { return i < E_ ? e[E_ + i] : i - E_; }

// one wave per (f, edge): score + atomic segment max
__global__ __launch_bounds__(256) void k_score(const float* __restrict__ Q,
        const float* __restrict__ K, const int* __restrict__ edges,
        float* __restrict__ score, unsigned* __restrict__ smax) {
    int wv = blockIdx.x * 4 + (threadIdx.x >> 6);
    int lane = threadIdx.x & 63;
    if (wv >= F_ * EP_) return;
    int f = wv / EP_, e = wv % EP_;
    int r = edge_row(edges, e), c = edge_col(edges, e);
    const float* Qr = Q + ((size_t)f * M_ + r) * T_;
    const float* Kc = K + ((size_t)f * M_ + c) * T_;
    float s = Qr[lane] * Kc[lane] + Qr[lane + 64] * Kc[lane + 64];
    #pragma unroll
    for (int mk = 32; mk >= 1; mk >>= 1) s += __shfl_xor(s, mk);
    s *= 0.0883883476483184f;   // 1/sqrt(128)
    if (lane == 0) {
        score[(size_t)f * EP_ + e] = s;
        atomicMax(&smax[f * M_ + r], fenc(s));
    }
}

__global__ void k_exden(float* __restrict__ score, const unsigned* __restrict__ smax,
                        float* __restrict__ den, const int* __restrict__ edges) {
    int i = blockIdx.x * blockDim.x + threadIdx.x;
    if (i >= F_ * EP_) return;
    int f = i / EP_, e = i % EP_;
    int r = edge_row(edges, e);
    float ex = expf(score[i] - fdec(smax[f * M_ + r]));
    score[i] = ex;
    atomicAdd(&den[f * M_ + r], ex);
}

// one wave per (f, edge): H[f][r][:] += V[f][c][:] * att
__global__ __launch_bounds__(256) void k_agg(const float* __restrict__ ex,
        const float* __restrict__ den, const float* __restrict__ V,
        const int* __restrict__ edges, float* __restrict__ H) {
    int wv = blockIdx.x * 4 + (threadIdx.x >> 6);
    int lane = threadIdx.x & 63;
    if (wv >= F_ * EP_) return;
    int f = wv / EP_, e = wv % EP_;
    int r = edge_row(edges, e), c = edge_col(edges, e);
    float att = ex[(size_t)f * EP_ + e] / den[f * M_ + r];
    const float* Vc = V + ((size_t)f * M_ + c) * T_;
    float* Hr = H + ((size_t)f * M_ + r) * T_;
    atomicAdd(&Hr[lane], Vc[lane] * att);
    atomicAdd(&Hr[lane + 64], Vc[lane + 64] * att);
}

// y_next[b,t,n,g] = H[g][b*N+n][t] + vb[g][t] + sum_f y[b,t,n,f]*rw[f][g] + rb[g]
__global__ void k_combine(const float* __restrict__ y, const float* __restrict__ H,
        const float* __restrict__ vb, const float* __restrict__ rw,
        const float* __restrict__ rb, const float* __restrict__ skw,
        const float* __restrict__ skb, int layer,
        float* __restrict__ ynext, float* __restrict__ sbuf) {
    int i = blockIdx.x * blockDim.x + threadIdx.x;
    if (i >= BTN_) return;
    int n = i % N_, t = (i / N_) % T_, bb = i / (N_ * T_);
    int m = bb * N_ + n;
    float yv[F_];
    const float4 y4 = *(const float4*)(y + (size_t)i * F_);
    yv[0] = y4.x; yv[1] = y4.y; yv[2] = y4.z; yv[3] = y4.w;
    float o[F_];
    #pragma unroll
    for (int g = 0; g < F_; ++g) {
        float acc = H[((size_t)g * M_ + m) * T_ + t] + vb[g * T_ + t] + rb[g];
        #pragma unroll
        for (int f2 = 0; f2 < F_; ++f2) acc += yv[f2] * rw[f2 * F_ + g];
        o[g] = acc;
    }
    float4 o4 = {o[0], o[1], o[2], o[3]};
    *(float4*)(ynext + (size_t)i * F_) = o4;
    float sk = skb[layer];
    #pragma unroll
    for (int g = 0; g < F_; ++g) sk += o[g] * skw[layer * F_ + g];
    sbuf[(size_t)i * L_ + layer] = lrelu(sk);
}

__global__ void k_final(const float* __restrict__ sbuf, const float* __restrict__ o1w,
        const float* __restrict__ o1b, const float* __restrict__ o2w,
        const float* __restrict__ o2b, float* __restrict__ out) {
    int i = blockIdx.x * blockDim.x + threadIdx.x;
    if (i >= BTN_) return;
    int n = i % N_, t = (i / N_) % T_, bb = i / (N_ * T_);
    float acc = o1b[0];
    #pragma unroll
    for (int dt = 0; dt < 3; ++dt) {
        int tt = t - 1 + dt;
        if (tt < 0 || tt >= T_) continue;
        #pragma unroll
        for (int dn = 0; dn < 3; ++dn) {
            int nn = n - 1 + dn;
            if (nn < 0 || nn >= N_) continue;
            const float* sp = sbuf + ((size_t)(bb * T_ + tt) * N_ + nn) * L_;
            #pragma unroll
            for (int l = 0; l < L_; ++l) acc += sp[l] * o1w[(dt * 3 + dn) * L_ + l];
        }
    }
    float g = lrelu(acc);
    out[i] = g * o2w[0] + o2b[0];
}

extern "C" void kernel_launch(void* const* d_in, const int* in_sizes, int n_in,
                              void* d_out, int out_size, void* d_ws, size_t ws_size,
                              hipStream_t stream) {
    const float* x       = (const float*)d_in[0];
    const int*   edges   = (const int*)d_in[1];
    const float* sd_w    = (const float*)d_in[2];
    const float* sd_b    = (const float*)d_in[3];
    const float* c1w     = (const float*)d_in[4];
    const float* c1b     = (const float*)d_in[5];
    const float* c2w     = (const float*)d_in[6];
    const float* c2b     = (const float*)d_in[7];
    const float* tcn_a_w = (const float*)d_in[8];
    const float* tcn_a_b = (const float*)d_in[9];
    const float* tcn_b_w = (const float*)d_in[10];
    const float* tcn_b_b = (const float*)d_in[11];
    const float* gat_q_w = (const float*)d_in[12];
    const float* gat_q_b = (const float*)d_in[13];
    const float* gat_k_w = (const float*)d_in[14];
    const float* gat_k_b = (const float*)d_in[15];
    const float* gat_v_w = (const float*)d_in[16];
    const float* gat_v_b = (const float*)d_in[17];
    const float* res_w   = (const float*)d_in[18];
    const float* res_b   = (const float*)d_in[19];
    const float* skip_w  = (const float*)d_in[20];
    const float* skip_b  = (const float*)d_in[21];
    const float* out1_w  = (const float*)d_in[22];
    const float* out1_b  = (const float*)d_in[23];
    const float* out2_w  = (const float*)d_in[24];
    const float* out2_b  = (const float*)d_in[25];
    float* out = (float*)d_out;

    float* ws = (float*)d_ws;
    size_t off = 0;
    auto alloc = [&](size_t nf) { float* p = ws + off; off += nf; return p; };
    float* ybuf  = alloc(SZ_);
    float* y2buf = alloc(SZ_);
    float* H     = alloc(SZ_);            // TCN b-partial s=1, later agg output
    float* apre  = alloc(SZ_);            // TCN a-partial s=0, later Q
    float* bpre  = alloc(SZ_);            // TCN b-partial s=0, later K
    float* V     = alloc(SZ_);            // TCN a-partial s=1, later V
    float* sbuf  = alloc((size_t)BTN_ * L_);
    float* y0    = alloc(MT_);
    float* y1    = alloc(BTN_);
    float* score = alloc((size_t)F_ * EP_);
    float* smax  = alloc((size_t)F_ * M_);
    float* den   = alloc((size_t)F_ * M_);
    unsigned short* xTn = (unsigned short*)alloc(SZ_ / 2);            // xT_bf / nodes_bf union
    unsigned short* wat = (unsigned short*)alloc((size_t)F_ * KTCN_ * N_ / 2);
    unsigned short* wbt = (unsigned short*)alloc((size_t)F_ * KTCN_ * N_ / 2);
    unsigned short* pwt = (unsigned short*)alloc((size_t)3 * F_ * T_ * T_ / 2);
    (void)ws_size; (void)in_sizes; (void)n_in; (void)out_size;

    // shunt
    k_dense<<<(B_ * T_ + 255) / 256, 256, 0, stream>>>(x, sd_w, sd_b, y0);
    k_conv1<<<(BTN_ + 255) / 256, 256, 0, stream>>>(y0, c1w, c1b, y1);
    k_conv2<<<(BTN_ + 255) / 256, 256, 0, stream>>>(y1, c2w, c2b, ybuf);

    float* cur = ybuf;
    float* nxt = y2buf;
    for (int layer = 0; layer < L_; ++layer) {
        const float* wa = tcn_a_w + (size_t)layer * F_ * KTCN_ * N_;
        const float* ba = tcn_a_b + (size_t)layer * F_ * N_;
        const float* wb = tcn_b_w + (size_t)layer * F_ * KTCN_ * N_;
        const float* bb = tcn_b_b + (size_t)layer * F_ * N_;
        const float* qw = gat_q_w + (size_t)layer * F_ * T_ * T_;
        const float* qb = gat_q_b + (size_t)layer * F_ * T_;
        const float* kw = gat_k_w + (size_t)layer * F_ * T_ * T_;
        const float* kbias = gat_k_b + (size_t)layer * F_ * T_;
        const float* vw = gat_v_w + (size_t)layer * F_ * T_ * T_;
        const float* vb = gat_v_b + (size_t)layer * F_ * T_;
        const float* rw = res_w + (size_t)layer * F_ * F_;
        const float* rb = res_b + (size_t)layer * F_;

        // input -> bf16 planes
        k_y2xt<<<(BTN_ + 255) / 256, 256, 0, stream>>>(cur, xTn);
        // weights -> bf16 transposed
        dim3 gw(N_ / 32, KTCN_ / 32, F_);
        k_convT<<<gw, 256, 0, stream>>>(wa, wat, KTCN_, N_);
        k_convT<<<gw, 256, 0, stream>>>(wb, wbt, KTCN_, N_);
        // TCN GEMMs: a/b fused, split-K=2 -> partials in {apre,V} (a) {bpre,H} (b)
        dim3 gt(N_ / 128, B_, 16);
        k_tcn_mfma<<<gt, 256, 0, stream>>>(xTn, wat, wbt, ba, bb, apre, V, bpre, H);
        // gating (partials summed) + transpose to nodes (overwrites xTn union)
        dim3 gg(T_ / 32, N_ / 32, F_ * B_);
        k_gate_nodes<<<gg, 256, 0, stream>>>(apre, V, bpre, H, xTn);
        // proj weights
        dim3 gpw(T_ / 32, T_ / 32, F_);
        const int PWOFF = F_ * T_ * T_;
        k_convT<<<gpw, 256, 0, stream>>>(qw, pwt, T_, T_);
        k_convT<<<gpw, 256, 0, stream>>>(kw, pwt + PWOFF, T_, T_);
        k_convT<<<gpw, 256, 0, stream>>>(vw, pwt + 2 * PWOFF, T_, T_);
        // projections fused: Q->apre, K->bpre, V->V
        dim3 gp(1, M_ / 128, 12);
        k_proj_mfma<<<gp, 256, 0, stream>>>(xTn, pwt, qb, kbias, apre, bpre, V);
        // GAT edge phase
        hipMemsetAsync(smax, 0, (size_t)F_ * M_ * 4, stream);
        hipMemsetAsync(den, 0, (size_t)F_ * M_ * 4, stream);
        hipMemsetAsync(H, 0, SZ_ * 4, stream);
        k_score<<<(F_ * EP_) / 4, 256, 0, stream>>>(apre, bpre, edges, score, (unsigned*)smax);
        k_exden<<<(F_ * EP_ + 255) / 256, 256, 0, stream>>>(score, (const unsigned*)smax, den, edges);
        k_agg<<<(F_ * EP_) / 4, 256, 0, stream>>>(score, den, V, edges, H);
        k_combine<<<(BTN_ + 255) / 256, 256, 0, stream>>>(cur, H, vb, rw, rb,
                skip_w, skip_b, layer, nxt, sbuf);
        float* tmp = cur; cur = nxt; nxt = tmp;
    }
    k_final<<<(BTN_ + 255) / 256, 256, 0, stream>>>(sbuf, out1_w, out1_b, out2_w, out2_b, out);
}

// Round 5
// 607.646 us; speedup vs baseline: 6.9432x; 1.2792x over previous
//
#include <hip/hip_runtime.h>
#include <math.h>

#define ALPHA_ 0.2f
#define AS1 __attribute__((address_space(1)))
#define AS3 __attribute__((address_space(3)))

constexpr int B_ = 8, LATENT_ = 256, T_ = 128, N_ = 768, F_ = 4, L_ = 3, E_ = 12288;
constexpr int M_ = B_ * N_;        // 6144 nodes
constexpr int MT_ = B_ * T_;       // 1024
constexpr int EP_ = E_ + M_;       // 18432 edges incl self loops
constexpr int BTN_ = B_ * T_ * N_; // 786432
constexpr size_t SZ_ = (size_t)BTN_ * F_;  // 3145728
constexpr int KTCN_ = 5 * N_;      // 3840
constexpr int KSPLIT_ = KTCN_ / 2; // 1920
constexpr int TP_ = T_ + 4;        // padded time dim (4 zero rows for causal)

typedef __bf16 bf16x8 __attribute__((ext_vector_type(8)));
typedef float f32x4 __attribute__((ext_vector_type(4)));

__device__ __forceinline__ float lrelu(float x) { return x > 0.0f ? x : ALPHA_ * x; }
__device__ __forceinline__ unsigned short f2bf(float x) {
    union { __bf16 h; unsigned short u; } c; c.h = (__bf16)x; return c.u;
}

// ---------------- shunt ----------------
__global__ void k_dense(const float* __restrict__ x, const float* __restrict__ w,
                        const float* __restrict__ b, float* __restrict__ y0) {
    int i = blockIdx.x * blockDim.x + threadIdx.x;
    if (i >= B_ * T_) return;
    int bb = i / T_, t = i % T_;
    float acc = b[t];
    for (int l = 0; l < LATENT_; ++l) acc += x[bb * LATENT_ + l] * w[l * T_ + t];
    y0[i] = acc;
}

__global__ void k_conv1(const float* __restrict__ y0, const float* __restrict__ w,
                        const float* __restrict__ b, float* __restrict__ y1) {
    int i = blockIdx.x * blockDim.x + threadIdx.x;
    if (i >= BTN_) return;
    int n = i % N_, t = (i / N_) % T_, bb = i / (N_ * T_);
    float acc = b[n];
    #pragma unroll
    for (int k = 0; k < 3; ++k) {
        int tt = t - 1 + k;
        if (tt >= 0 && tt < T_) acc += y0[bb * T_ + tt] * w[k * N_ + n];
    }
    y1[i] = acc;
}

// conv2 + write fp32 interleaved y AND bf16 padded planes for TCN A
__global__ void k_conv2w(const float* __restrict__ y1, const float* __restrict__ w,
                         const float* __restrict__ b, float* __restrict__ y,
                         unsigned short* __restrict__ xTpad) {
    int i = blockIdx.x * blockDim.x + threadIdx.x;
    if (i >= BTN_) return;
    int n = i % N_, t = (i / N_) % T_, bb = i / (N_ * T_);
    float acc[F_];
    #pragma unroll
    for (int f = 0; f < F_; ++f) acc[f] = b[f];
    #pragma unroll
    for (int dt = 0; dt < 3; ++dt) {
        int tt = t - 1 + dt;
        if (tt < 0 || tt >= T_) continue;
        #pragma unroll
        for (int dn = 0; dn < 3; ++dn) {
            int nn = n - 1 + dn;
            if (nn < 0 || nn >= N_) continue;
            float v = y1[(bb * T_ + tt) * N_ + nn];
            #pragma unroll
            for (int f = 0; f < F_; ++f) acc[f] += v * w[(dt * 3 + dn) * F_ + f];
        }
    }
    #pragma unroll
    for (int f = 0; f < F_; ++f) {
        y[(size_t)i * F_ + f] = acc[f];
        xTpad[((size_t)(f * B_ + bb) * TP_ + 4 + t) * N_ + n] = f2bf(acc[f]);
    }
}

// outT[f][n][k] = bf16(in[f][k][n]); grid (Nd/32, Kd/32, F)
__global__ __launch_bounds__(256) void k_convT(const float* __restrict__ in,
        unsigned short* __restrict__ outT, int Kd, int Nd) {
    __shared__ float tl[32][33];
    const int f = blockIdx.z;
    in += (size_t)f * Kd * Nd;
    outT += (size_t)f * Kd * Nd;
    const int x0 = blockIdx.x * 32;   // n
    const int y0 = blockIdx.y * 32;   // k
    const int tx = threadIdx.x & 31, ty = threadIdx.x >> 5;
    #pragma unroll
    for (int r = 0; r < 4; ++r)
        tl[ty + r * 8][tx] = in[(size_t)(y0 + ty + r * 8) * Nd + x0 + tx];
    __syncthreads();
    #pragma unroll
    for (int r = 0; r < 4; ++r)
        outT[(size_t)(x0 + ty + r * 8) * Kd + y0 + tx] = f2bf(tl[tx][ty + r * 8]);
}

// ---------------- TCN GEMM (bf16 MFMA, global_load_lds, a/b fused, split-K=2) ----
__global__ __launch_bounds__(256) void k_tcn_mfma(
        const unsigned short* __restrict__ xTpad,
        const unsigned short* __restrict__ wat, const unsigned short* __restrict__ wbt,
        const float* __restrict__ ba, const float* __restrict__ bbias,
        float* __restrict__ oa0, float* __restrict__ oa1,
        float* __restrict__ ob0, float* __restrict__ ob1) {
    __shared__ unsigned short As[128 * 32];
    __shared__ unsigned short Bs[128 * 32];
    const int zz = blockIdx.z;
    const int f = zz & 3;
    const int wsel = (zz >> 2) & 1;
    const int s = zz >> 3;
    const int n0 = blockIdx.x * 128;
    const int bt = blockIdx.y;                       // m-tile == one batch
    const unsigned short* xf = xTpad + (size_t)(f * B_ + bt) * TP_ * N_;
    const unsigned short* wf = (wsel ? wbt : wat) + (size_t)f * N_ * KTCN_ + (size_t)n0 * KTCN_;
    const float* bias = (wsel ? bbias : ba) + f * N_;
    float* out = (wsel ? (s ? ob1 : ob0) : (s ? oa1 : oa0));
    const int tid = threadIdx.x;
    const int lane = tid & 63;
    const int w = tid >> 6;
    const int wm = (w >> 1) * 64, wn = (w & 1) * 64;
    const int r16 = lane & 15, kb = lane >> 4;
    const int srow = lane >> 2;                      // 0..15
    const int scol = (lane & 3) * 8;                 // shorts
    f32x4 acc[4][4] = {};
    const int k_lo = s * KSPLIT_, k_hi = k_lo + KSPLIT_;
    for (int kk0 = k_lo; kk0 < k_hi; kk0 += 32) {
        const int ks = kk0 / N_;                     // 32|768 -> constant per chunk
        const int nin0 = kk0 - ks * N_;
        #pragma unroll
        for (int h = 0; h < 2; ++h) {
            const int seg = w + 4 * h;
            const int row = seg * 16 + srow;
            const unsigned short* gA = xf + (size_t)(row + ks) * N_ + nin0 + scol;
            const unsigned short* gB = wf + (size_t)row * KTCN_ + kk0 + scol;
            __builtin_amdgcn_global_load_lds((const AS1 unsigned int*)(const void*)gA,
                    (AS3 unsigned int*)(void*)(As + seg * 512), 16, 0, 0);
            __builtin_amdgcn_global_load_lds((const AS1 unsigned int*)(const void*)gB,
                    (AS3 unsigned int*)(void*)(Bs + seg * 512), 16, 0, 0);
        }
        __syncthreads();
        bf16x8 av[4], bv[4];
        #pragma unroll
        for (int i = 0; i < 4; ++i) av[i] = *(const bf16x8*)(As + (wm + i * 16 + r16) * 32 + kb * 8);
        #pragma unroll
        for (int j = 0; j < 4; ++j) bv[j] = *(const bf16x8*)(Bs + (wn + j * 16 + r16) * 32 + kb * 8);
        #pragma unroll
        for (int i = 0; i < 4; ++i)
            #pragma unroll
            for (int j = 0; j < 4; ++j)
                acc[i][j] = __builtin_amdgcn_mfma_f32_16x16x32_bf16(av[i], bv[j], acc[i][j], 0, 0, 0);
        __syncthreads();
    }
    float* of = out + (size_t)(f * B_ + bt) * T_ * N_;
    #pragma unroll
    for (int i = 0; i < 4; ++i) {
        #pragma unroll
        for (int j = 0; j < 4; ++j) {
            const int n = n0 + wn + j * 16 + r16;
            const float bv2 = (s == 0) ? bias[n] : 0.0f;
            #pragma unroll
            for (int r = 0; r < 4; ++r) {
                const int m = wm + i * 16 + kb * 4 + r;
                of[(size_t)m * N_ + n] = acc[i][j][r] + bv2;
            }
        }
    }
}

// ---------------- gating (sum split-K partials) + transpose to node layout --------
__global__ __launch_bounds__(256) void k_gate_nodes(const float* __restrict__ a0,
        const float* __restrict__ a1, const float* __restrict__ b0,
        const float* __restrict__ b1, unsigned short* __restrict__ nodes) {
    __shared__ float tl[32][33];
    const int bz = blockIdx.z;                       // f*B + b
    const int t0 = blockIdx.x * 32, n0 = blockIdx.y * 32;
    const int tx = threadIdx.x & 31, ty = threadIdx.x >> 5;
    const size_t base = (size_t)bz * T_ * N_;
    #pragma unroll
    for (int r = 0; r < 4; ++r) {
        const size_t idx = base + (size_t)(t0 + ty + r * 8) * N_ + n0 + tx;
        const float av = a0[idx] + a1[idx], bvv = b0[idx] + b1[idx];
        tl[ty + r * 8][tx] = (1.0f / (1.0f + __expf(-av))) * tanhf(bvv);
    }
    __syncthreads();
    #pragma unroll
    for (int r = 0; r < 4; ++r)
        nodes[base + (size_t)(n0 + ty + r * 8) * T_ + t0 + tx] = f2bf(tl[tx][ty + r * 8]);
}

// ---------------- GAT projection GEMM (gl_lds, Q/K/V fused) ----------------------
__global__ __launch_bounds__(256) void k_proj_mfma(
        const unsigned short* __restrict__ nodes, const unsigned short* __restrict__ pwt,
        const float* __restrict__ qb, const float* __restrict__ kbias,
        float* __restrict__ Q, float* __restrict__ K, float* __restrict__ V) {
    __shared__ unsigned short As[128 * 32];
    __shared__ unsigned short Bs[128 * 32];
    const int zz = blockIdx.z;
    const int f = zz & 3;
    const int sel = zz >> 2;
    const int m0 = blockIdx.y * 128;
    const unsigned short* af = nodes + (size_t)f * M_ * T_;
    const unsigned short* wfp = pwt + (size_t)sel * F_ * T_ * T_ + (size_t)f * T_ * T_;
    const float* bias = (sel == 0) ? qb : (sel == 1 ? kbias : nullptr);
    float* out = (sel == 0) ? Q : (sel == 1 ? K : V);
    const int tid = threadIdx.x;
    const int lane = tid & 63;
    const int w = tid >> 6;
    const int wm = (w >> 1) * 64, wn = (w & 1) * 64;
    const int r16 = lane & 15, kb = lane >> 4;
    const int srow = lane >> 2;
    const int scol = (lane & 3) * 8;
    f32x4 acc[4][4] = {};
    for (int kk0 = 0; kk0 < T_; kk0 += 32) {
        #pragma unroll
        for (int h = 0; h < 2; ++h) {
            const int seg = w + 4 * h;
            const int row = seg * 16 + srow;
            const unsigned short* gA = af + (size_t)(m0 + row) * T_ + kk0 + scol;
            const unsigned short* gB = wfp + (size_t)row * T_ + kk0 + scol;
            __builtin_amdgcn_global_load_lds((const AS1 unsigned int*)(const void*)gA,
                    (AS3 unsigned int*)(void*)(As + seg * 512), 16, 0, 0);
            __builtin_amdgcn_global_load_lds((const AS1 unsigned int*)(const void*)gB,
                    (AS3 unsigned int*)(void*)(Bs + seg * 512), 16, 0, 0);
        }
        __syncthreads();
        bf16x8 av[4], bv[4];
        #pragma unroll
        for (int i = 0; i < 4; ++i) av[i] = *(const bf16x8*)(As + (wm + i * 16 + r16) * 32 + kb * 8);
        #pragma unroll
        for (int j = 0; j < 4; ++j) bv[j] = *(const bf16x8*)(Bs + (wn + j * 16 + r16) * 32 + kb * 8);
        #pragma unroll
        for (int i = 0; i < 4; ++i)
            #pragma unroll
            for (int j = 0; j < 4; ++j)
                acc[i][j] = __builtin_amdgcn_mfma_f32_16x16x32_bf16(av[i], bv[j], acc[i][j], 0, 0, 0);
        __syncthreads();
    }
    const int do_l = (sel < 2);
    float* of = out + (size_t)f * M_ * T_;
    #pragma unroll
    for (int i = 0; i < 4; ++i) {
        #pragma unroll
        for (int j = 0; j < 4; ++j) {
            const int n = wn + j * 16 + r16;
            #pragma unroll
            for (int r = 0; r < 4; ++r) {
                const int m = m0 + wm + i * 16 + kb * 4 + r;
                float v = acc[i][j][r];
                if (bias) v += bias[f * T_ + n];
                if (do_l) v = lrelu(v);
                of[(size_t)m * T_ + n] = v;
            }
        }
    }
}

// ---------------- CSR build (once; graph shared across f and layers) --------------
__device__ __forceinline__ int edge_row(const int* e, int i) { return i < E_ ? e[i] : i - E_; }
__device__ __forceinline__ int edge_col(const int* e, int i) { return i < E_ ? e[E_ + i] : i - E_; }

__global__ void k_hist(const int* __restrict__ edges, int* __restrict__ deg) {
    int i = blockIdx.x * blockDim.x + threadIdx.x;
    if (i >= EP_) return;
    atomicAdd(&deg[edge_row(edges, i)], 1);
}

__global__ __launch_bounds__(256) void k_scan(const int* __restrict__ deg,
        int* __restrict__ rowptr, int* __restrict__ cursor) {
    __shared__ int part[256];
    const int tid = threadIdx.x;
    constexpr int PER = M_ / 256;   // 24
    int loc[PER];
    int s = 0;
    #pragma unroll
    for (int j = 0; j < PER; ++j) { loc[j] = s; s += deg[tid * PER + j]; }
    part[tid] = s;
    __syncthreads();
    if (tid == 0) {
        int run = 0;
        for (int i2 = 0; i2 < 256; ++i2) { int v = part[i2]; part[i2] = run; run += v; }
        rowptr[M_] = run;
    }
    __syncthreads();
    const int off = part[tid];
    #pragma unroll
    for (int j = 0; j < PER; ++j) {
        rowptr[tid * PER + j] = off + loc[j];
        cursor[tid * PER + j] = off + loc[j];
    }
}

__global__ void k_scatter(const int* __restrict__ edges, int* __restrict__ cursor,
                          int* __restrict__ csr_col) {
    int i = blockIdx.x * blockDim.x + threadIdx.x;
    if (i >= EP_) return;
    int r = edge_row(edges, i), c = edge_col(edges, i);
    int pos = atomicAdd(&cursor[r], 1);
    csr_col[pos] = c;
}

// ---------------- fused GAT: scores + softmax + aggregate, one wave per (f,row) ---
__global__ __launch_bounds__(256) void k_gat(const float* __restrict__ Q,
        const float* __restrict__ Kb, const float* __restrict__ V,
        const int* __restrict__ rowptr, const int* __restrict__ csr_col,
        float* __restrict__ H) {
    constexpr int CAP = 128;
    __shared__ float sc[4][CAP];
    const int w = threadIdx.x >> 6, lane = threadIdx.x & 63;
    const int wv = blockIdx.x * 4 + w;
    const int f = wv / M_, r = wv - f * M_;
    const int p0 = rowptr[r], p1 = rowptr[r + 1];
    const float* Qr = Q + ((size_t)f * M_ + r) * T_;
    const float q0 = Qr[lane], q1 = Qr[lane + 64];
    float mx = -3.4e38f;
    for (int j = p0; j < p1; ++j) {
        const float* Kc = Kb + ((size_t)f * M_ + csr_col[j]) * T_;
        float s = q0 * Kc[lane] + q1 * Kc[lane + 64];
        #pragma unroll
        for (int mk = 32; mk >= 1; mk >>= 1) s += __shfl_xor(s, mk);
        s *= 0.0883883476483184f;
        if (lane == 0 && j - p0 < CAP) sc[w][j - p0] = s;
        mx = fmaxf(mx, s);
    }
    float den = 0.0f;
    for (int j = p0; j < p1; ++j) {
        float s;
        if (j - p0 < CAP) s = sc[w][j - p0];
        else {
            const float* Kc = Kb + ((size_t)f * M_ + csr_col[j]) * T_;
            s = q0 * Kc[lane] + q1 * Kc[lane + 64];
            #pragma unroll
            for (int mk = 32; mk >= 1; mk >>= 1) s += __shfl_xor(s, mk);
            s *= 0.0883883476483184f;
        }
        den += __expf(s - mx);
    }
    const float rden = 1.0f / den;
    float a0 = 0.0f, a1 = 0.0f;
    for (int j = p0; j < p1; ++j) {
        const int c = csr_col[j];
        float s;
        if (j - p0 < CAP) s = sc[w][j - p0];
        else {
            const float* Kc = Kb + ((size_t)f * M_ + c) * T_;
            s = q0 * Kc[lane] + q1 * Kc[lane + 64];
            #pragma unroll
            for (int mk = 32; mk >= 1; mk >>= 1) s += __shfl_xor(s, mk);
            s *= 0.0883883476483184f;
        }
        const float att = __expf(s - mx) * rden;
        const float* Vc = V + ((size_t)f * M_ + c) * T_;
        a0 += att * Vc[lane];
        a1 += att * Vc[lane + 64];
    }
    float* Hr = H + ((size_t)f * M_ + r) * T_;
    Hr[lane] = a0;
    Hr[lane + 64] = a1;
}

// ---------------- combine: residual + skip + bf16 xTpad for next layer ------------
// tiled so both H ([f][b][n][t]) and y ([b][t][n][f]) sides coalesce
__global__ __launch_bounds__(256) void k_combine_t(const float* __restrict__ y,
        const float* __restrict__ H, const float* __restrict__ vb,
        const float* __restrict__ rw, const float* __restrict__ rb,
        const float* __restrict__ skw, const float* __restrict__ skb, int layer,
        float* __restrict__ ynext, unsigned short* __restrict__ xTpad,
        float* __restrict__ sbufp) {
    __shared__ float hl[F_][32][33];
    const int b = blockIdx.z;
    const int t0 = blockIdx.x * 32, n0 = blockIdx.y * 32;
    const int tx = threadIdx.x & 31, ty = threadIdx.x >> 5;
    #pragma unroll
    for (int g = 0; g < F_; ++g)
        #pragma unroll
        for (int r = 0; r < 4; ++r) {
            const int nn = ty + r * 8;
            hl[g][nn][tx] = H[((size_t)g * M_ + b * N_ + n0 + nn) * T_ + t0 + tx];
        }
    __syncthreads();
    #pragma unroll
    for (int r = 0; r < 4; ++r) {
        const int tt = ty + r * 8;
        const int t = t0 + tt;
        const size_t i = ((size_t)b * T_ + t) * N_ + n0 + tx;
        const float4 y4 = *(const float4*)(y + i * 4);
        float o[F_];
        #pragma unroll
        for (int g = 0; g < F_; ++g) {
            float acc = hl[g][tx][tt] + vb[g * T_ + t] + rb[g];
            acc += y4.x * rw[0 * F_ + g] + y4.y * rw[1 * F_ + g]
                 + y4.z * rw[2 * F_ + g] + y4.w * rw[3 * F_ + g];
            o[g] = acc;
        }
        float4 o4 = {o[0], o[1], o[2], o[3]};
        *(float4*)(ynext + i * 4) = o4;
        #pragma unroll
        for (int g = 0; g < F_; ++g)
            xTpad[((size_t)(g * B_ + b) * TP_ + 4 + t) * N_ + n0 + tx] = f2bf(o[g]);
        float sk = skb[layer];
        #pragma unroll
        for (int g = 0; g < F_; ++g) sk += o[g] * skw[layer * F_ + g];
        sbufp[(size_t)layer * BTN_ + i] = lrelu(sk);
    }
}

__global__ void k_final(const float* __restrict__ sbufp, const float* __restrict__ o1w,
        const float* __restrict__ o1b, const float* __restrict__ o2w,
        const float* __restrict__ o2b, float* __restrict__ out) {
    int i = blockIdx.x * blockDim.x + threadIdx.x;
    if (i >= BTN_) return;
    int n = i % N_, t = (i / N_) % T_, bb = i / (N_ * T_);
    float acc = o1b[0];
    #pragma unroll
    for (int dt = 0; dt < 3; ++dt) {
        int tt = t - 1 + dt;
        if (tt < 0 || tt >= T_) continue;
        #pragma unroll
        for (int dn = 0; dn < 3; ++dn) {
            int nn = n - 1 + dn;
            if (nn < 0 || nn >= N_) continue;
            const size_t base = (size_t)(bb * T_ + tt) * N_ + nn;
            #pragma unroll
            for (int l = 0; l < L_; ++l)
                acc += sbufp[(size_t)l * BTN_ + base] * o1w[(dt * 3 + dn) * L_ + l];
        }
    }
    float g = lrelu(acc);
    out[i] = g * o2w[0] + o2b[0];
}

extern "C" void kernel_launch(void* const* d_in, const int* in_sizes, int n_in,
                              void* d_out, int out_size, void* d_ws, size_t ws_size,
                              hipStream_t stream) {
    const float* x       = (const float*)d_in[0];
    const int*   edges   = (const int*)d_in[1];
    const float* sd_w    = (const float*)d_in[2];
    const float* sd_b    = (const float*)d_in[3];
    const float* c1w     = (const float*)d_in[4];
    const float* c1b     = (const float*)d_in[5];
    const float* c2w     = (const float*)d_in[6];
    const float* c2b     = (const float*)d_in[7];
    const float* tcn_a_w = (const float*)d_in[8];
    const float* tcn_a_b = (const float*)d_in[9];
    const float* tcn_b_w = (const float*)d_in[10];
    const float* tcn_b_b = (const float*)d_in[11];
    const float* gat_q_w = (const float*)d_in[12];
    const float* gat_q_b = (const float*)d_in[13];
    const float* gat_k_w = (const float*)d_in[14];
    const float* gat_k_b = (const float*)d_in[15];
    const float* gat_v_w = (const float*)d_in[16];
    const float* gat_v_b = (const float*)d_in[17];
    const float* res_w   = (const float*)d_in[18];
    const float* res_b   = (const float*)d_in[19];
    const float* skip_w  = (const float*)d_in[20];
    const float* skip_b  = (const float*)d_in[21];
    const float* out1_w  = (const float*)d_in[22];
    const float* out1_b  = (const float*)d_in[23];
    const float* out2_w  = (const float*)d_in[24];
    const float* out2_b  = (const float*)d_in[25];
    float* out = (float*)d_out;

    float* ws = (float*)d_ws;
    size_t off = 0;
    auto alloc = [&](size_t nf) { float* p = ws + off; off += nf; return p; };
    float* ybuf  = alloc(SZ_);
    float* y2buf = alloc(SZ_);
    float* H     = alloc(SZ_);            // TCN b-partial s=1, then GAT output
    float* apre  = alloc(SZ_);            // TCN a-partial s=0, then Q
    float* bpre  = alloc(SZ_);            // TCN b-partial s=0, then K
    float* V     = alloc(SZ_);            // TCN a-partial s=1, then V
    float* sbufp = alloc((size_t)BTN_ * L_);
    float* y0    = alloc(MT_);
    float* y1    = alloc(BTN_);
    unsigned short* xTpad  = (unsigned short*)alloc((size_t)F_ * B_ * TP_ * N_ / 2 + 16);
    unsigned short* nodesb = (unsigned short*)alloc(SZ_ / 2);
    unsigned short* wat = (unsigned short*)alloc((size_t)F_ * KTCN_ * N_ / 2);
    unsigned short* wbt = (unsigned short*)alloc((size_t)F_ * KTCN_ * N_ / 2);
    unsigned short* pwt = (unsigned short*)alloc((size_t)3 * F_ * T_ * T_ / 2);
    int* rowptr  = (int*)alloc(M_ + 1);
    int* cursor  = (int*)alloc(M_);
    int* deg     = (int*)alloc(M_);
    int* csr_col = (int*)alloc(EP_);
    (void)ws_size; (void)in_sizes; (void)n_in; (void)out_size;

    // zero padded activation buffer once (pad rows stay zero forever)
    hipMemsetAsync(xTpad, 0, (size_t)F_ * B_ * TP_ * N_ * 2, stream);
    // CSR build (graph is layer/f independent)
    hipMemsetAsync(deg, 0, M_ * 4, stream);
    k_hist<<<(EP_ + 255) / 256, 256, 0, stream>>>(edges, deg);
    k_scan<<<1, 256, 0, stream>>>(deg, rowptr, cursor);
    k_scatter<<<(EP_ + 255) / 256, 256, 0, stream>>>(edges, cursor, csr_col);

    // shunt
    k_dense<<<(B_ * T_ + 255) / 256, 256, 0, stream>>>(x, sd_w, sd_b, y0);
    k_conv1<<<(BTN_ + 255) / 256, 256, 0, stream>>>(y0, c1w, c1b, y1);
    k_conv2w<<<(BTN_ + 255) / 256, 256, 0, stream>>>(y1, c2w, c2b, ybuf, xTpad);

    float* cur = ybuf;
    float* nxt = y2buf;
    for (int layer = 0; layer < L_; ++layer) {
        const float* wa = tcn_a_w + (size_t)layer * F_ * KTCN_ * N_;
        const float* ba = tcn_a_b + (size_t)layer * F_ * N_;
        const float* wb = tcn_b_w + (size_t)layer * F_ * KTCN_ * N_;
        const float* bb = tcn_b_b + (size_t)layer * F_ * N_;
        const float* qw = gat_q_w + (size_t)layer * F_ * T_ * T_;
        const float* qb = gat_q_b + (size_t)layer * F_ * T_;
        const float* kw = gat_k_w + (size_t)layer * F_ * T_ * T_;
        const float* kbias = gat_k_b + (size_t)layer * F_ * T_;
        const float* vw = gat_v_w + (size_t)layer * F_ * T_ * T_;
        const float* vb = gat_v_b + (size_t)layer * F_ * T_;
        const float* rw = res_w + (size_t)layer * F_ * F_;
        const float* rb = res_b + (size_t)layer * F_;

        // TCN weights -> bf16 transposed
        dim3 gw(N_ / 32, KTCN_ / 32, F_);
        k_convT<<<gw, 256, 0, stream>>>(wa, wat, KTCN_, N_);
        k_convT<<<gw, 256, 0, stream>>>(wb, wbt, KTCN_, N_);
        // TCN GEMMs: a/b fused, split-K=2 -> partials {apre,V} (a) {bpre,H} (b)
        dim3 gt(N_ / 128, B_, 16);
        k_tcn_mfma<<<gt, 256, 0, stream>>>(xTpad, wat, wbt, ba, bb, apre, V, bpre, H);
        // gating (+partial sum) + transpose -> bf16 nodes
        dim3 gg(T_ / 32, N_ / 32, F_ * B_);
        k_gate_nodes<<<gg, 256, 0, stream>>>(apre, V, bpre, H, nodesb);
        // proj weights -> bf16 transposed
        dim3 gpw(T_ / 32, T_ / 32, F_);
        const int PWOFF = F_ * T_ * T_;
        k_convT<<<gpw, 256, 0, stream>>>(qw, pwt, T_, T_);
        k_convT<<<gpw, 256, 0, stream>>>(kw, pwt + PWOFF, T_, T_);
        k_convT<<<gpw, 256, 0, stream>>>(vw, pwt + 2 * PWOFF, T_, T_);
        // projections fused: Q->apre, K->bpre, V->V
        dim3 gp(1, M_ / 128, 12);
        k_proj_mfma<<<gp, 256, 0, stream>>>(nodesb, pwt, qb, kbias, apre, bpre, V);
        // fused GAT (no atomics, no memsets)
        k_gat<<<(F_ * M_) / 4, 256, 0, stream>>>(apre, bpre, V, rowptr, csr_col, H);
        // combine + next-layer bf16 planes + skip plane
        dim3 gc(T_ / 32, N_ / 32, B_);
        k_combine_t<<<gc, 256, 0, stream>>>(cur, H, vb, rw, rb, skip_w, skip_b,
                layer, nxt, xTpad, sbufp);
        float* tmp = cur; cur = nxt; nxt = tmp;
    }
    k_final<<<(BTN_ + 255) / 256, 256, 0, stream>>>(sbufp, out1_w, out1_b, out2_w, out2_b, out);
}